// Round 1
// baseline (1091.926 us; speedup 1.0000x reference)
//
#include <hip/hip_runtime.h>

// Problem constants (fixed shapes from setup_inputs)
#define HS   48
#define WSB  48
#define NPIX 2304        // 48*48
#define CCH  128         // c
#define NT   6           // n*t
#define CIN  258         // 2c+2
#define HH   192
#define WW   192

// ws layout in floats.
// Early-phase buffers (extra, xa, xb, offs, araw) all die before k_gather runs,
// so out_img (9,437,184 floats) overlaps them at offset 0. attnw/sidx live
// during k_gather and sit above out_img. Total ws need: 39.5 MB.
#define EXTRA_OFF 0ull
#define XA_OFF    3566592ull   // extra: 6*258*2304
#define XB_OFF    5336064ull   // xa: 2*6*64*2304
#define OFFS_OFF  7105536ull   // xb: same
#define ARAW_OFF  7547904ull   // offs: 6*32*2304
#define OUTIMG_OFF 0ull
#define ATTNW_OFF 9437184ull   // out_img: 2*128*192*192
#define SIDX_OFF  9658368ull   // attnw: 8*2304*12

static __device__ __forceinline__ float leaky_f(float v) { return v >= 0.f ? v : 0.1f * v; }

// ---- K1: extra[:,0:128] = per-16-channel mean of sp at own pixel ----
__global__ __launch_bounds__(256) void k_avgpool(const float* __restrict__ sp,
                                                 float* __restrict__ extra) {
    int idx = blockIdx.x * 256 + threadIdx.x;
    if (idx >= NT * CCH * NPIX) return;
    int pix = idx % NPIX;
    int cc  = (idx / NPIX) % CCH;
    int nt  = idx / (NPIX * CCH);
    const float* p = sp + ((size_t)nt * 2048 + (size_t)cc * 16) * NPIX + pix;
    float s = 0.f;
#pragma unroll
    for (int k = 0; k < 16; k++) s += p[(size_t)k * NPIX];
    extra[((size_t)nt * CIN + cc) * NPIX + pix] = s * 0.0625f;
}

// ---- K2: extra[:,128:256] = gather of pooled field at flow-sampled pixel; [256:258]=flow ----
__global__ __launch_bounds__(256) void k_extra_rest(const float* __restrict__ flow,
                                                    float* __restrict__ extra) {
    int idx = blockIdx.x * 256 + threadIdx.x;
    if (idx >= NT * 130 * NPIX) return;
    int pix = idx % NPIX;
    int cc  = (idx / NPIX) % 130;
    int nt  = idx / (NPIX * 130);
    float fx = flow[((size_t)nt * 2 + 0) * NPIX + pix];
    float fy = flow[((size_t)nt * 2 + 1) * NPIX + pix];
    if (cc >= 128) {
        extra[((size_t)nt * CIN + 256 + (cc - 128)) * NPIX + pix] = (cc == 128) ? fx : fy;
        return;
    }
    int x = pix % WSB, y = pix / WSB;
    float locx = fx + (float)x;
    float locy = fy + (float)y;
    // exact replication of reference normalization chain (align_corners grid1)
    float gfx = 2.0f * locx / 47.0f - 1.0f;
    float gfy = 2.0f * locy / 47.0f - 1.0f;
    float rx = rintf(((gfx + 1.0f) * 0.5f) * 47.0f);
    float ry = rintf(((gfy + 1.0f) * 0.5f) * 47.0f);
    bool valid = (rx >= 0.f) && (rx <= 47.f) && (ry >= 0.f) && (ry <= 47.f);
    int sx = (int)fminf(fmaxf(rx, 0.f), 47.f);
    int sy = (int)fminf(fmaxf(ry, 0.f), 47.f);
    float v = valid ? extra[((size_t)nt * CIN + cc) * NPIX + sy * WSB + sx] : 0.f;
    extra[((size_t)nt * CIN + 128 + cc) * NPIX + pix] = v;
}

// ---- K3: 1x1 conv 258->64 + leaky, both nets (z = net*4+ocg) ----
__global__ __launch_bounds__(256) void k_conv1x1_l0(const float* __restrict__ extra,
                                                    const float* __restrict__ w_so, const float* __restrict__ b_so,
                                                    const float* __restrict__ w_aw, const float* __restrict__ b_aw,
                                                    float* __restrict__ xa) {
    __shared__ float ws_[16 * CIN];
    int tile = blockIdx.x;          // 0..8
    int nt   = blockIdx.y;          // 0..5
    int z    = blockIdx.z;          // 0..7
    int net = z >> 2, ocg = z & 3;
    const float* wsel = net ? w_aw : w_so;
    const float* bsel = net ? b_aw : b_so;
    for (int i = threadIdx.x; i < 16 * CIN; i += 256)
        ws_[i] = wsel[(size_t)(ocg * 16) * CIN + i];
    __syncthreads();
    int pix = tile * 256 + threadIdx.x;
    float acc[16];
#pragma unroll
    for (int o = 0; o < 16; o++) acc[o] = bsel[ocg * 16 + o];
    const float* in = extra + (size_t)nt * CIN * NPIX + pix;
    for (int ci = 0; ci < CIN; ci++) {
        float v = in[(size_t)ci * NPIX];
#pragma unroll
        for (int o = 0; o < 16; o++) acc[o] = fmaf(ws_[o * CIN + ci], v, acc[o]);
    }
    float* op = xa + (((size_t)net * NT + nt) * 64 + ocg * 16) * NPIX + pix;
#pragma unroll
    for (int o = 0; o < 16; o++) op[(size_t)o * NPIX] = leaky_f(acc[o]);
}

// ---- K4: 3x3 conv 64->64 pad1 + leaky, both nets ----
__global__ __launch_bounds__(256) void k_conv3x3(const float* __restrict__ xin,
                                                 const float* __restrict__ w_so, const float* __restrict__ b_so,
                                                 const float* __restrict__ w_aw, const float* __restrict__ b_aw,
                                                 float* __restrict__ xout) {
    __shared__ float tile[18][19];
    int tid = threadIdx.x;
    int tx = tid & 15, ty = tid >> 4;
    int tileid = blockIdx.x;                    // 0..8 (3x3 of 16x16)
    int tx0 = (tileid % 3) * 16, ty0 = (tileid / 3) * 16;
    int nt = blockIdx.y;
    int z = blockIdx.z;
    int net = z >> 2, ocg = z & 3;
    const float* w = net ? w_aw : w_so;
    const float* b = net ? b_aw : b_so;
    const float* in = xin + ((size_t)net * NT + nt) * 64 * NPIX;
    float acc[16];
#pragma unroll
    for (int o = 0; o < 16; o++) acc[o] = b[ocg * 16 + o];
    for (int ic = 0; ic < 64; ic++) {
        for (int i = tid; i < 18 * 18; i += 256) {
            int iy = i / 18, ix = i % 18;
            int gy = ty0 + iy - 1, gx = tx0 + ix - 1;
            float v = 0.f;
            if (gy >= 0 && gy < HS && gx >= 0 && gx < WSB)
                v = in[(size_t)ic * NPIX + gy * WSB + gx];
            tile[iy][ix] = v;
        }
        __syncthreads();
        float pv[3][3];
#pragma unroll
        for (int dy = 0; dy < 3; dy++)
#pragma unroll
            for (int dx = 0; dx < 3; dx++)
                pv[dy][dx] = tile[ty + dy][tx + dx];
        const float* wp = w + ((size_t)(ocg * 16) * 64 + ic) * 9;
#pragma unroll
        for (int o = 0; o < 16; o++)
#pragma unroll
            for (int tap = 0; tap < 9; tap++)
                acc[o] = fmaf(wp[(size_t)o * 64 * 9 + tap], pv[tap / 3][tap % 3], acc[o]);
        __syncthreads();
    }
    int pix = (ty0 + ty) * WSB + (tx0 + tx);
    float* op = xout + (((size_t)net * NT + nt) * 64 + ocg * 16) * NPIX + pix;
#pragma unroll
    for (int o = 0; o < 16; o++) op[(size_t)o * NPIX] = leaky_f(acc[o]);
}

// ---- K5: final 1x1 convs (no activation): so 64->32 -> offsets, aw 64->16 -> attnraw ----
__global__ __launch_bounds__(256) void k_conv1x1_l3(const float* __restrict__ xin,
                                                    const float* __restrict__ w_so, const float* __restrict__ b_so,
                                                    const float* __restrict__ w_aw, const float* __restrict__ b_aw,
                                                    float* __restrict__ offs, float* __restrict__ araw) {
    int pix = blockIdx.x * 256 + threadIdx.x;
    int nt = blockIdx.y;
    int net = blockIdx.z;
    const float* in = xin + ((size_t)net * NT + nt) * 64 * NPIX + pix;
    if (net == 0) {
        float acc[32];
#pragma unroll
        for (int o = 0; o < 32; o++) acc[o] = b_so[o];
        for (int ci = 0; ci < 64; ci++) {
            float v = in[(size_t)ci * NPIX];
#pragma unroll
            for (int o = 0; o < 32; o++) acc[o] = fmaf(w_so[o * 64 + ci], v, acc[o]);
        }
#pragma unroll
        for (int o = 0; o < 32; o++) offs[((size_t)nt * 32 + o) * NPIX + pix] = acc[o];
    } else {
        float acc[16];
#pragma unroll
        for (int o = 0; o < 16; o++) acc[o] = b_aw[o];
        for (int ci = 0; ci < 64; ci++) {
            float v = in[(size_t)ci * NPIX];
#pragma unroll
            for (int o = 0; o < 16; o++) acc[o] = fmaf(w_aw[o * 64 + ci], v, acc[o]);
        }
#pragma unroll
        for (int o = 0; o < 16; o++) araw[((size_t)nt * 16 + o) * NPIX + pix] = acc[o];
    }
}

// ---- K6: softmax over 12 (t,p) + sample-index precompute ----
__global__ __launch_bounds__(256) void k_softmax_idx(const float* __restrict__ araw,
                                                     const float* __restrict__ offs,
                                                     const float* __restrict__ flow,
                                                     float* __restrict__ attnw, int* __restrict__ sidx) {
    int idx = blockIdx.x * 256 + threadIdx.x;   // (n*4+head)*NPIX + pix
    if (idx >= 2 * 4 * NPIX) return;
    int pix  = idx % NPIX;
    int head = (idx / NPIX) & 3;
    int n    = idx / (NPIX * 4);
    int x = pix % WSB, y = pix / WSB;
    float a[12];
#pragma unroll
    for (int t = 0; t < 3; t++)
#pragma unroll
        for (int p = 0; p < 4; p++)
            a[t * 4 + p] = araw[(((size_t)(n * 3 + t)) * 16 + head * 4 + p) * NPIX + pix];
    float mx = a[0];
#pragma unroll
    for (int k = 1; k < 12; k++) mx = fmaxf(mx, a[k]);
    float ssum = 0.f;
#pragma unroll
    for (int k = 0; k < 12; k++) { a[k] = expf(a[k] - mx); ssum += a[k]; }
    float inv = 1.0f / ssum;
#pragma unroll
    for (int t = 0; t < 3; t++) {
        int nt = n * 3 + t;
        float fx = flow[((size_t)nt * 2 + 0) * NPIX + pix];
        float fy = flow[((size_t)nt * 2 + 1) * NPIX + pix];
        float locx = fx + (float)x;
        float locy = fy + (float)y;
#pragma unroll
        for (int p = 0; p < 4; p++) {
            int hp = head * 4 + p;
            float gx_ = locx + offs[(((size_t)nt) * 32 + hp * 2 + 0) * NPIX + pix];
            float gy_ = locy + offs[(((size_t)nt) * 32 + hp * 2 + 1) * NPIX + pix];
            // exact replication: divide-by-dim normalization, then (g+1)*0.5*(dim-1)
            float ngx = 2.0f * gx_ / 48.0f - 1.0f;
            float ngy = 2.0f * gy_ / 48.0f - 1.0f;
            float rx = rintf(((ngx + 1.0f) * 0.5f) * 47.0f);
            float ry = rintf(((ngy + 1.0f) * 0.5f) * 47.0f);
            bool valid = (rx >= 0.f) && (rx <= 47.f) && (ry >= 0.f) && (ry <= 47.f);
            int sx = (int)fminf(fmaxf(rx, 0.f), 47.f);
            int sy = (int)fminf(fmaxf(ry, 0.f), 47.f);
            int k = t * 4 + p;
            attnw[(size_t)idx * 12 + k] = valid ? a[k] * inv : 0.f;
            sidx[(size_t)idx * 12 + k]  = sy * WSB + sx;
        }
    }
}

// ---- K7: 12-term gather-weighted sum, written directly in folded NCHW ----
__global__ __launch_bounds__(256) void k_gather(const float* __restrict__ sp,
                                                const float* __restrict__ attnw,
                                                const int* __restrict__ sidx,
                                                float* __restrict__ outimg) {
    size_t idx = (size_t)blockIdx.x * 256 + threadIdx.x;   // over 2*128*192*192
    int wq = (int)(idx % WW);
    int hq = (int)((idx / WW) % HH);
    int oc = (int)((idx / ((size_t)WW * HH)) % CCH);
    int n  = (int)(idx / ((size_t)WW * HH * CCH));
    int head = oc >> 5, cc = oc & 31;
    int y = hq >> 2, s1 = hq & 3, x = wq >> 2, s2 = wq & 3;
    int ch = head * 512 + cc * 16 + s1 * 4 + s2;   // sp channel (unfold identity)
    int pix = y * WSB + x;
    size_t ab = ((size_t)(n * 4 + head) * NPIX + pix) * 12;
    float acc = 0.f;
#pragma unroll
    for (int t = 0; t < 3; t++) {
        const float* spb = sp + ((size_t)(n * 3 + t) * 2048 + ch) * NPIX;
#pragma unroll
        for (int p = 0; p < 4; p++) {
            int k = t * 4 + p;
            acc = fmaf(attnw[ab + k], spb[sidx[ab + k]], acc);
        }
    }
    outimg[idx] = acc;
}

// ---- K8: fusion 3x3 conv 128->128 pad1 + bias + anchor residual ----
__global__ __launch_bounds__(256) void k_fusion(const float* __restrict__ xin,
                                                const float* __restrict__ wf,
                                                const float* __restrict__ bf,
                                                const float* __restrict__ anchor,
                                                float* __restrict__ out) {
    __shared__ float tile[4][34][36];
    int tid = threadIdx.x;
    int ttx = tid & 15, tty = tid >> 4;
    int tI = blockIdx.x;                     // 0..35 (6x6 of 32x32)
    int tx0 = (tI % 6) * 32, ty0 = (tI / 6) * 32;
    int ocg = blockIdx.y;                    // 16 groups of 8
    int n = blockIdx.z;
    const float* inb = xin + (size_t)n * CCH * HH * WW;
    float acc[8][2][2] = {};
    for (int icc = 0; icc < CCH; icc += 4) {
        for (int i = tid; i < 4 * 34 * 34; i += 256) {
            int ic = i / (34 * 34);
            int r = i % (34 * 34);
            int iy = r / 34, ix = r % 34;
            int gy = ty0 + iy - 1, gx = tx0 + ix - 1;
            float v = 0.f;
            if (gy >= 0 && gy < HH && gx >= 0 && gx < WW)
                v = inb[(size_t)(icc + ic) * HH * WW + (size_t)gy * WW + gx];
            tile[ic][iy][ix] = v;
        }
        __syncthreads();
#pragma unroll
        for (int ic = 0; ic < 4; ic++) {
            float pv[4][2][3];
#pragma unroll
            for (int r = 0; r < 4; r++)
#pragma unroll
                for (int sxn = 0; sxn < 2; sxn++)
#pragma unroll
                    for (int cx = 0; cx < 3; cx++)
                        pv[r][sxn][cx] = tile[ic][2 * tty + r][ttx + 16 * sxn + cx];
            const float* wp = wf + ((size_t)(ocg * 8) * CCH + (icc + ic)) * 9;
#pragma unroll
            for (int o = 0; o < 8; o++) {
                float wv[9];
#pragma unroll
                for (int q = 0; q < 9; q++) wv[q] = wp[(size_t)o * CCH * 9 + q];
#pragma unroll
                for (int sy = 0; sy < 2; sy++)
#pragma unroll
                    for (int sxn = 0; sxn < 2; sxn++)
#pragma unroll
                        for (int ky = 0; ky < 3; ky++)
#pragma unroll
                            for (int kx = 0; kx < 3; kx++)
                                acc[o][sy][sxn] = fmaf(wv[ky * 3 + kx], pv[sy + ky][sxn][kx], acc[o][sy][sxn]);
            }
        }
        __syncthreads();
    }
#pragma unroll
    for (int o = 0; o < 8; o++) {
        int oc = ocg * 8 + o;
        float bv = bf[oc];
#pragma unroll
        for (int sy = 0; sy < 2; sy++) {
            int gy = ty0 + 2 * tty + sy;
#pragma unroll
            for (int sxn = 0; sxn < 2; sxn++) {
                int gx = tx0 + ttx + 16 * sxn;
                size_t oidx = ((size_t)n * CCH + oc) * HH * WW + (size_t)gy * WW + gx;
                out[oidx] = acc[o][sy][sxn] + bv + anchor[oidx];
            }
        }
    }
}

extern "C" void kernel_launch(void* const* d_in, const int* in_sizes, int n_in,
                              void* d_out, int out_size, void* d_ws, size_t ws_size,
                              hipStream_t stream) {
    (void)in_sizes; (void)n_in; (void)out_size; (void)ws_size;
    const float* anchor = (const float*)d_in[1];
    const float* sp     = (const float*)d_in[2];
    const float* flow   = (const float*)d_in[3];
    const float* so_w0 = (const float*)d_in[4];  const float* so_b0 = (const float*)d_in[5];
    const float* so_w1 = (const float*)d_in[6];  const float* so_b1 = (const float*)d_in[7];
    const float* so_w2 = (const float*)d_in[8];  const float* so_b2 = (const float*)d_in[9];
    const float* so_w3 = (const float*)d_in[10]; const float* so_b3 = (const float*)d_in[11];
    const float* aw_w0 = (const float*)d_in[12]; const float* aw_b0 = (const float*)d_in[13];
    const float* aw_w1 = (const float*)d_in[14]; const float* aw_b1 = (const float*)d_in[15];
    const float* aw_w2 = (const float*)d_in[16]; const float* aw_b2 = (const float*)d_in[17];
    const float* aw_w3 = (const float*)d_in[18]; const float* aw_b3 = (const float*)d_in[19];
    const float* fw    = (const float*)d_in[20]; const float* fb    = (const float*)d_in[21];

    float* ws     = (float*)d_ws;
    float* extra  = ws + EXTRA_OFF;
    float* xa     = ws + XA_OFF;
    float* xb     = ws + XB_OFF;
    float* offs   = ws + OFFS_OFF;
    float* araw   = ws + ARAW_OFF;
    float* outimg = ws + OUTIMG_OFF;
    float* attnw  = ws + ATTNW_OFF;
    int*   sidx   = (int*)(ws + SIDX_OFF);
    float* outp   = (float*)d_out;

    k_avgpool<<<dim3((NT * CCH * NPIX + 255) / 256), 256, 0, stream>>>(sp, extra);
    k_extra_rest<<<dim3((NT * 130 * NPIX + 255) / 256), 256, 0, stream>>>(flow, extra);
    k_conv1x1_l0<<<dim3(9, 6, 8), 256, 0, stream>>>(extra, so_w0, so_b0, aw_w0, aw_b0, xa);
    k_conv3x3<<<dim3(9, 6, 8), 256, 0, stream>>>(xa, so_w1, so_b1, aw_w1, aw_b1, xb);
    k_conv3x3<<<dim3(9, 6, 8), 256, 0, stream>>>(xb, so_w2, so_b2, aw_w2, aw_b2, xa);
    k_conv1x1_l3<<<dim3(9, 6, 2), 256, 0, stream>>>(xa, so_w3, so_b3, aw_w3, aw_b3, offs, araw);
    k_softmax_idx<<<dim3((2 * 4 * NPIX + 255) / 256), 256, 0, stream>>>(araw, offs, flow, attnw, sidx);
    k_gather<<<dim3((2 * CCH * HH * WW) / 256), 256, 0, stream>>>(sp, attnw, sidx, outimg);
    k_fusion<<<dim3(36, 16, 2), 256, 0, stream>>>(outimg, fw, fb, anchor, outp);
}

// Round 2
// 640.814 us; speedup vs baseline: 1.7040x; 1.7040x over previous
//
#include <hip/hip_runtime.h>

typedef unsigned short u16;
typedef unsigned int u32;
typedef __attribute__((ext_vector_type(8))) short bf16x8;
typedef __attribute__((ext_vector_type(4))) float f32x4;

// Problem constants (fixed shapes from setup_inputs)
#define HS   48
#define WSB  48
#define NPIX 2304        // 48*48
#define CCH  128         // c
#define NT   6           // n*t
#define CIN  258         // 2c+2
#define HH   192
#define WW   192

// ws layout in f32 slots. Lifetimes:
//   extra:K1-K3  xa/xb:K3-K5  offs/araw:K5-K6  attnw/sidx:K6-K7
//   outimg(bf16):K7-K8 (overlaps dead extra/xa region)  wbf:K0-K8
#define EXTRA_OFF  0ull
#define XA_OFF     3566592ull   // extra: 6*258*2304
#define XB_OFF     5336064ull
#define OFFS_OFF   7105536ull
#define ARAW_OFF   7547904ull   // offs: 6*32*2304
#define ATTNW_OFF  7769088ull   // araw: 6*16*2304
#define SIDX_OFF   7990272ull   // attnw: 8*2304*12
#define WBF_OFF    8211456ull   // sidx: 8*2304*12 ; wbf: 9*128*128 bf16 = 73728 f32
#define OUTIMG_OFF 0ull         // bf16 2*192*192*128 = 4,718,592 f32 slots
// total ws need: 8,285,184 f32 = 33.1 MB (round-1 proved >= 39.5 MB available)

static __device__ __forceinline__ float leaky_f(float v) { return v >= 0.f ? v : 0.1f * v; }
static __device__ __forceinline__ u16 f2bf(float f) {
    u32 u = __float_as_uint(f);
    u = (u + 0x7fffu + ((u >> 16) & 1u)) >> 16;
    return (u16)u;
}

// ---- K0: pack fusion weights to bf16 [d][oc][ic] ----
__global__ __launch_bounds__(256) void k_wprep(const float* __restrict__ fw, u16* __restrict__ wbf) {
    int i = blockIdx.x * 256 + threadIdx.x;      // 9*128*128 = 147456
    int d = i / 16384;
    int r2 = i & 16383;
    int oc = r2 >> 7, ic = r2 & 127;
    wbf[i] = f2bf(fw[((size_t)oc * 128 + ic) * 9 + d]);
}

// ---- K1: extra[:,0:128] = per-16-channel mean of sp at own pixel ----
__global__ __launch_bounds__(256) void k_avgpool(const float* __restrict__ sp,
                                                 float* __restrict__ extra) {
    int idx = blockIdx.x * 256 + threadIdx.x;
    if (idx >= NT * CCH * NPIX) return;
    int pix = idx % NPIX;
    int cc  = (idx / NPIX) % CCH;
    int nt  = idx / (NPIX * CCH);
    const float* p = sp + ((size_t)nt * 2048 + (size_t)cc * 16) * NPIX + pix;
    float s = 0.f;
#pragma unroll
    for (int k = 0; k < 16; k++) s += p[(size_t)k * NPIX];
    extra[((size_t)nt * CIN + cc) * NPIX + pix] = s * 0.0625f;
}

// ---- K2: extra[:,128:256] = gather of pooled field at flow-sampled pixel; [256:258]=flow ----
__global__ __launch_bounds__(256) void k_extra_rest(const float* __restrict__ flow,
                                                    float* __restrict__ extra) {
    int idx = blockIdx.x * 256 + threadIdx.x;
    if (idx >= NT * 130 * NPIX) return;
    int pix = idx % NPIX;
    int cc  = (idx / NPIX) % 130;
    int nt  = idx / (NPIX * 130);
    float fx = flow[((size_t)nt * 2 + 0) * NPIX + pix];
    float fy = flow[((size_t)nt * 2 + 1) * NPIX + pix];
    if (cc >= 128) {
        extra[((size_t)nt * CIN + 256 + (cc - 128)) * NPIX + pix] = (cc == 128) ? fx : fy;
        return;
    }
    int x = pix % WSB, y = pix / WSB;
    float locx = fx + (float)x;
    float locy = fy + (float)y;
    float gfx = 2.0f * locx / 47.0f - 1.0f;
    float gfy = 2.0f * locy / 47.0f - 1.0f;
    float rx = rintf(((gfx + 1.0f) * 0.5f) * 47.0f);
    float ry = rintf(((gfy + 1.0f) * 0.5f) * 47.0f);
    bool valid = (rx >= 0.f) && (rx <= 47.f) && (ry >= 0.f) && (ry <= 47.f);
    int sx = (int)fminf(fmaxf(rx, 0.f), 47.f);
    int sy = (int)fminf(fmaxf(ry, 0.f), 47.f);
    float v = valid ? extra[((size_t)nt * CIN + cc) * NPIX + sy * WSB + sx] : 0.f;
    extra[((size_t)nt * CIN + 128 + cc) * NPIX + pix] = v;
}

// ---- K3: 1x1 conv 258->64 + leaky, both nets (z = net*4+ocg) ----
__global__ __launch_bounds__(256) void k_conv1x1_l0(const float* __restrict__ extra,
                                                    const float* __restrict__ w_so, const float* __restrict__ b_so,
                                                    const float* __restrict__ w_aw, const float* __restrict__ b_aw,
                                                    float* __restrict__ xa) {
    __shared__ float ws_[16 * CIN];
    int tile = blockIdx.x;
    int nt   = blockIdx.y;
    int z    = blockIdx.z;
    int net = z >> 2, ocg = z & 3;
    const float* wsel = net ? w_aw : w_so;
    const float* bsel = net ? b_aw : b_so;
    for (int i = threadIdx.x; i < 16 * CIN; i += 256)
        ws_[i] = wsel[(size_t)(ocg * 16) * CIN + i];
    __syncthreads();
    int pix = tile * 256 + threadIdx.x;
    float acc[16];
#pragma unroll
    for (int o = 0; o < 16; o++) acc[o] = bsel[ocg * 16 + o];
    const float* in = extra + (size_t)nt * CIN * NPIX + pix;
    for (int ci = 0; ci < CIN; ci++) {
        float v = in[(size_t)ci * NPIX];
#pragma unroll
        for (int o = 0; o < 16; o++) acc[o] = fmaf(ws_[o * CIN + ci], v, acc[o]);
    }
    float* op = xa + (((size_t)net * NT + nt) * 64 + ocg * 16) * NPIX + pix;
#pragma unroll
    for (int o = 0; o < 16; o++) op[(size_t)o * NPIX] = leaky_f(acc[o]);
}

// ---- K4: 3x3 conv 64->64 pad1 + leaky, both nets ----
__global__ __launch_bounds__(256) void k_conv3x3(const float* __restrict__ xin,
                                                 const float* __restrict__ w_so, const float* __restrict__ b_so,
                                                 const float* __restrict__ w_aw, const float* __restrict__ b_aw,
                                                 float* __restrict__ xout) {
    __shared__ float tile[18][19];
    int tid = threadIdx.x;
    int tx = tid & 15, ty = tid >> 4;
    int tileid = blockIdx.x;
    int tx0 = (tileid % 3) * 16, ty0 = (tileid / 3) * 16;
    int nt = blockIdx.y;
    int z = blockIdx.z;
    int net = z >> 2, ocg = z & 3;
    const float* w = net ? w_aw : w_so;
    const float* b = net ? b_aw : b_so;
    const float* in = xin + ((size_t)net * NT + nt) * 64 * NPIX;
    float acc[16];
#pragma unroll
    for (int o = 0; o < 16; o++) acc[o] = b[ocg * 16 + o];
    for (int ic = 0; ic < 64; ic++) {
        for (int i = tid; i < 18 * 18; i += 256) {
            int iy = i / 18, ix = i % 18;
            int gy = ty0 + iy - 1, gx = tx0 + ix - 1;
            float v = 0.f;
            if (gy >= 0 && gy < HS && gx >= 0 && gx < WSB)
                v = in[(size_t)ic * NPIX + gy * WSB + gx];
            tile[iy][ix] = v;
        }
        __syncthreads();
        float pv[3][3];
#pragma unroll
        for (int dy = 0; dy < 3; dy++)
#pragma unroll
            for (int dx = 0; dx < 3; dx++)
                pv[dy][dx] = tile[ty + dy][tx + dx];
        const float* wp = w + ((size_t)(ocg * 16) * 64 + ic) * 9;
#pragma unroll
        for (int o = 0; o < 16; o++)
#pragma unroll
            for (int tap = 0; tap < 9; tap++)
                acc[o] = fmaf(wp[(size_t)o * 64 * 9 + tap], pv[tap / 3][tap % 3], acc[o]);
        __syncthreads();
    }
    int pix = (ty0 + ty) * WSB + (tx0 + tx);
    float* op = xout + (((size_t)net * NT + nt) * 64 + ocg * 16) * NPIX + pix;
#pragma unroll
    for (int o = 0; o < 16; o++) op[(size_t)o * NPIX] = leaky_f(acc[o]);
}

// ---- K5: final 1x1 convs ----
__global__ __launch_bounds__(256) void k_conv1x1_l3(const float* __restrict__ xin,
                                                    const float* __restrict__ w_so, const float* __restrict__ b_so,
                                                    const float* __restrict__ w_aw, const float* __restrict__ b_aw,
                                                    float* __restrict__ offs, float* __restrict__ araw) {
    int pix = blockIdx.x * 256 + threadIdx.x;
    int nt = blockIdx.y;
    int net = blockIdx.z;
    const float* in = xin + ((size_t)net * NT + nt) * 64 * NPIX + pix;
    if (net == 0) {
        float acc[32];
#pragma unroll
        for (int o = 0; o < 32; o++) acc[o] = b_so[o];
        for (int ci = 0; ci < 64; ci++) {
            float v = in[(size_t)ci * NPIX];
#pragma unroll
            for (int o = 0; o < 32; o++) acc[o] = fmaf(w_so[o * 64 + ci], v, acc[o]);
        }
#pragma unroll
        for (int o = 0; o < 32; o++) offs[((size_t)nt * 32 + o) * NPIX + pix] = acc[o];
    } else {
        float acc[16];
#pragma unroll
        for (int o = 0; o < 16; o++) acc[o] = b_aw[o];
        for (int ci = 0; ci < 64; ci++) {
            float v = in[(size_t)ci * NPIX];
#pragma unroll
            for (int o = 0; o < 16; o++) acc[o] = fmaf(w_aw[o * 64 + ci], v, acc[o]);
        }
#pragma unroll
        for (int o = 0; o < 16; o++) araw[((size_t)nt * 16 + o) * NPIX + pix] = acc[o];
    }
}

// ---- K6: softmax over 12 (t,p) + sample-index precompute ----
__global__ __launch_bounds__(256) void k_softmax_idx(const float* __restrict__ araw,
                                                     const float* __restrict__ offs,
                                                     const float* __restrict__ flow,
                                                     float* __restrict__ attnw, int* __restrict__ sidx) {
    int idx = blockIdx.x * 256 + threadIdx.x;
    if (idx >= 2 * 4 * NPIX) return;
    int pix  = idx % NPIX;
    int head = (idx / NPIX) & 3;
    int n    = idx / (NPIX * 4);
    int x = pix % WSB, y = pix / WSB;
    float a[12];
#pragma unroll
    for (int t = 0; t < 3; t++)
#pragma unroll
        for (int p = 0; p < 4; p++)
            a[t * 4 + p] = araw[(((size_t)(n * 3 + t)) * 16 + head * 4 + p) * NPIX + pix];
    float mx = a[0];
#pragma unroll
    for (int k = 1; k < 12; k++) mx = fmaxf(mx, a[k]);
    float ssum = 0.f;
#pragma unroll
    for (int k = 0; k < 12; k++) { a[k] = expf(a[k] - mx); ssum += a[k]; }
    float inv = 1.0f / ssum;
#pragma unroll
    for (int t = 0; t < 3; t++) {
        int nt = n * 3 + t;
        float fx = flow[((size_t)nt * 2 + 0) * NPIX + pix];
        float fy = flow[((size_t)nt * 2 + 1) * NPIX + pix];
        float locx = fx + (float)x;
        float locy = fy + (float)y;
#pragma unroll
        for (int p = 0; p < 4; p++) {
            int hp = head * 4 + p;
            float gx_ = locx + offs[(((size_t)nt) * 32 + hp * 2 + 0) * NPIX + pix];
            float gy_ = locy + offs[(((size_t)nt) * 32 + hp * 2 + 1) * NPIX + pix];
            float ngx = 2.0f * gx_ / 48.0f - 1.0f;
            float ngy = 2.0f * gy_ / 48.0f - 1.0f;
            float rx = rintf(((ngx + 1.0f) * 0.5f) * 47.0f);
            float ry = rintf(((ngy + 1.0f) * 0.5f) * 47.0f);
            bool valid = (rx >= 0.f) && (rx <= 47.f) && (ry >= 0.f) && (ry <= 47.f);
            int sx = (int)fminf(fmaxf(rx, 0.f), 47.f);
            int sy = (int)fminf(fmaxf(ry, 0.f), 47.f);
            int k = t * 4 + p;
            attnw[(size_t)idx * 12 + k] = valid ? a[k] * inv : 0.f;
            sidx[(size_t)idx * 12 + k]  = sy * WSB + sx;
        }
    }
}

// ---- K7: 12-term gather-weighted sum -> bf16 NHWC image ----
__global__ __launch_bounds__(256) void k_gather_bf16(const float* __restrict__ sp,
                                                     const float* __restrict__ attnw,
                                                     const int* __restrict__ sidx,
                                                     u16* __restrict__ outimg) {
    int t0 = blockIdx.x * 256 + threadIdx.x;   // over 2*192*192*128
    int oc = t0 & 127;
    int gp = t0 >> 7;
    int n = gp / (HH * WW);
    int rem = gp % (HH * WW);
    int hq = rem / WW, wq = rem % WW;
    int head = oc >> 5, cc = oc & 31;
    int ch = head * 512 + cc * 16 + (hq & 3) * 4 + (wq & 3);
    int pix = (hq >> 2) * WSB + (wq >> 2);
    size_t ab = ((size_t)(n * 4 + head) * NPIX + pix) * 12;
    float acc = 0.f;
#pragma unroll
    for (int t = 0; t < 3; t++) {
        const float* spb = sp + ((size_t)(n * 3 + t) * 2048 + ch) * NPIX;
#pragma unroll
        for (int p = 0; p < 4; p++) {
            int k = t * 4 + p;
            acc = fmaf(attnw[ab + k], spb[sidx[ab + k]], acc);
        }
    }
    outimg[t0] = f2bf(acc);
}

// ---- K8: fusion 3x3 conv 128->128 via bf16 MFMA implicit GEMM ----
// Block: 4 waves, tile = 128 pixels (8y x 16x) x 128 oc. Per wave 4x4 frags 16x16x32.
__global__ __launch_bounds__(256, 2) void k_fusion_mfma(const u16* __restrict__ img,   // bf16 NHWC
                                                        const u16* __restrict__ wbf,   // bf16 [9][oc][ic]
                                                        const float* __restrict__ bias,
                                                        const float* __restrict__ anchor,
                                                        float* __restrict__ out) {
    __shared__ __align__(16) u16 lds_in[180 * 128];   // 46080 B, halo 10x18 rows x 128 ic, swizzled
    __shared__ __align__(16) u16 lds_w[128 * 128];    // 32768 B, [oc][ic] per tap, swizzled

    const int tid = threadIdx.x;
    const int px0 = blockIdx.x * 16;
    const int py0 = blockIdx.y * 8;
    const int nb  = blockIdx.z;
    const int lane = tid & 63;
    const int wave = tid >> 6;
    const int wm = wave >> 1, wn = wave & 1;
    const int r = lane & 15, g = lane >> 4;

    char* lin_b = reinterpret_cast<char*>(lds_in);
    char* lw_b  = reinterpret_cast<char*>(lds_w);

    // stage input halo (global bf16 NHWC -> LDS swizzled)
    for (int i = tid; i < 180 * 16; i += 256) {
        int p = i >> 4, c16 = i & 15;
        int hy = p / 18, hx = p % 18;
        int gy = py0 + hy - 1, gx = px0 + hx - 1;
        int4 v = make_int4(0, 0, 0, 0);
        if (gy >= 0 && gy < HH && gx >= 0 && gx < WW)
            v = *reinterpret_cast<const int4*>(img + (((size_t)(nb * HH + gy) * WW + gx) << 7) + (c16 << 3));
        *reinterpret_cast<int4*>(lin_b + p * 256 + (((c16 ^ (p & 7)) << 4))) = v;
    }

    // per-m pixel coords, per-n oc bases
    int pym[4], pxm[4], ocn[4];
#pragma unroll
    for (int m = 0; m < 4; m++) { int p = wm * 64 + m * 16 + r; pym[m] = p >> 4; pxm[m] = p & 15; }
#pragma unroll
    for (int n = 0; n < 4; n++) ocn[n] = wn * 64 + n * 16 + r;

    f32x4 acc[4][4] = {};
    int4 wr[8];
    // prefetch tap-0 weights into regs
#pragma unroll
    for (int q = 0; q < 8; q++)
        wr[q] = *reinterpret_cast<const int4*>(wbf + (size_t)(tid + q * 256) * 8);

    for (int d = 0; d < 9; d++) {
        // write prefetched weights to LDS (swizzled)
#pragma unroll
        for (int q = 0; q < 8; q++) {
            int j = tid + q * 256;
            int oc = j >> 4, c16 = j & 15;
            *reinterpret_cast<int4*>(lw_b + oc * 256 + (((c16 ^ (oc & 7)) << 4))) = wr[q];
        }
        __syncthreads();
        if (d < 8) {
#pragma unroll
            for (int q = 0; q < 8; q++)
                wr[q] = *reinterpret_cast<const int4*>(wbf + (size_t)(d + 1) * 16384 + (size_t)(tid + q * 256) * 8);
        }
        int dy = d / 3, dx = d % 3;
#pragma unroll
        for (int kc = 0; kc < 4; kc++) {
            int c16 = kc * 4 + g;
            bf16x8 a[4], b[4];
#pragma unroll
            for (int m = 0; m < 4; m++) {
                int hp = (pym[m] + dy) * 18 + (pxm[m] + dx);
                a[m] = *reinterpret_cast<const bf16x8*>(lin_b + hp * 256 + (((c16 ^ (hp & 7)) << 4)));
            }
#pragma unroll
            for (int n = 0; n < 4; n++)
                b[n] = *reinterpret_cast<const bf16x8*>(lw_b + ocn[n] * 256 + (((c16 ^ (ocn[n] & 7)) << 4)));
#pragma unroll
            for (int m = 0; m < 4; m++)
#pragma unroll
                for (int n = 0; n < 4; n++)
                    acc[m][n] = __builtin_amdgcn_mfma_f32_16x16x32_bf16(a[m], b[n], acc[m][n], 0, 0, 0);
        }
        __syncthreads();
    }

    // epilogue: transpose through LDS (reuse lds_w) -> coalesced NCHW stores
    float* buf = reinterpret_cast<float*>(lds_w);   // [128 oc][17]
    for (int mg = 0; mg < 8; mg++) {
        if (wm == (mg >> 2)) {
            int m = mg & 3;
#pragma unroll
            for (int n = 0; n < 4; n++) {
                int oc = ocn[n];
#pragma unroll
                for (int reg = 0; reg < 4; reg++)
                    buf[oc * 17 + g * 4 + reg] = acc[m][n][reg];
            }
        }
        __syncthreads();
        {
            int pxl = tid & 15;
            int ocq = tid >> 4;
            int gy = py0 + mg;
#pragma unroll
            for (int q = 0; q < 8; q++) {
                int oc = ocq + q * 16;
                float v = buf[oc * 17 + pxl];
                size_t oa = ((size_t)(nb * CCH + oc)) * (HH * WW) + (size_t)gy * WW + px0 + pxl;
                out[oa] = v + bias[oc] + anchor[oa];
            }
        }
        __syncthreads();
    }
}

extern "C" void kernel_launch(void* const* d_in, const int* in_sizes, int n_in,
                              void* d_out, int out_size, void* d_ws, size_t ws_size,
                              hipStream_t stream) {
    (void)in_sizes; (void)n_in; (void)out_size; (void)ws_size;
    const float* anchor = (const float*)d_in[1];
    const float* sp     = (const float*)d_in[2];
    const float* flow   = (const float*)d_in[3];
    const float* so_w0 = (const float*)d_in[4];  const float* so_b0 = (const float*)d_in[5];
    const float* so_w1 = (const float*)d_in[6];  const float* so_b1 = (const float*)d_in[7];
    const float* so_w2 = (const float*)d_in[8];  const float* so_b2 = (const float*)d_in[9];
    const float* so_w3 = (const float*)d_in[10]; const float* so_b3 = (const float*)d_in[11];
    const float* aw_w0 = (const float*)d_in[12]; const float* aw_b0 = (const float*)d_in[13];
    const float* aw_w1 = (const float*)d_in[14]; const float* aw_b1 = (const float*)d_in[15];
    const float* aw_w2 = (const float*)d_in[16]; const float* aw_b2 = (const float*)d_in[17];
    const float* aw_w3 = (const float*)d_in[18]; const float* aw_b3 = (const float*)d_in[19];
    const float* fw    = (const float*)d_in[20]; const float* fb    = (const float*)d_in[21];

    float* ws     = (float*)d_ws;
    float* extra  = ws + EXTRA_OFF;
    float* xa     = ws + XA_OFF;
    float* xb     = ws + XB_OFF;
    float* offs   = ws + OFFS_OFF;
    float* araw   = ws + ARAW_OFF;
    float* attnw  = ws + ATTNW_OFF;
    int*   sidx   = (int*)(ws + SIDX_OFF);
    u16*   wbf    = (u16*)(ws + WBF_OFF);
    u16*   outimg = (u16*)(ws + OUTIMG_OFF);
    float* outp   = (float*)d_out;

    k_wprep<<<dim3(576), 256, 0, stream>>>(fw, wbf);
    k_avgpool<<<dim3((NT * CCH * NPIX + 255) / 256), 256, 0, stream>>>(sp, extra);
    k_extra_rest<<<dim3((NT * 130 * NPIX + 255) / 256), 256, 0, stream>>>(flow, extra);
    k_conv1x1_l0<<<dim3(9, 6, 8), 256, 0, stream>>>(extra, so_w0, so_b0, aw_w0, aw_b0, xa);
    k_conv3x3<<<dim3(9, 6, 8), 256, 0, stream>>>(xa, so_w1, so_b1, aw_w1, aw_b1, xb);
    k_conv3x3<<<dim3(9, 6, 8), 256, 0, stream>>>(xb, so_w2, so_b2, aw_w2, aw_b2, xa);
    k_conv1x1_l3<<<dim3(9, 6, 2), 256, 0, stream>>>(xa, so_w3, so_b3, aw_w3, aw_b3, offs, araw);
    k_softmax_idx<<<dim3((2 * 4 * NPIX + 255) / 256), 256, 0, stream>>>(araw, offs, flow, attnw, sidx);
    k_gather_bf16<<<dim3(2 * HH * WW * CCH / 256), 256, 0, stream>>>(sp, attnw, sidx, outimg);
    k_fusion_mfma<<<dim3(WW / 16, HH / 8, 2), 256, 0, stream>>>(outimg, wbf, fb, anchor, outp);
}

// Round 3
// 469.975 us; speedup vs baseline: 2.3234x; 1.3635x over previous
//
#include <hip/hip_runtime.h>

typedef unsigned short u16;
typedef unsigned int u32;
typedef __attribute__((ext_vector_type(8))) short bf16x8;
typedef __attribute__((ext_vector_type(4))) float f32x4;

// Problem constants (fixed shapes from setup_inputs)
#define HS   48
#define WSB  48
#define NPIX 2304        // 48*48
#define CCH  128         // c
#define NT   6           // n*t
#define CIN  258         // 2c+2
#define HH   192
#define WW   192

// ws layout in f32 slots. Lifetimes:
//   extra:   K1-K3      [0, 3,566,592)
//   outimg:  K7-K8      [0, 4,718,592)  (bf16; overlaps dead extra)
//   xa:      K3-K5      [4,718,592, 6,488,064)
//   xb:      K4-K5      [6,488,064, 8,257,536)
//   offs:    K5-K6      [8,257,536, 8,699,904)
//   araw:    K5-K6      [8,699,904, 8,921,088)
//   spT:     T(n)-G(n)  [4,718,592, 11,796,480)  (bf16 3*2304*2048; overlaps dead xa/xb/offs/araw)
//   attnw:   K6-K7      [11,796,480, 12,017,664)
//   sidx:    K6-K7      [12,017,664, 12,238,848)
//   wbf:     K0-K8      [12,238,848, 12,312,576)
// total: 12,312,576 f32 = 49.3 MB
#define EXTRA_OFF  0ull
#define OUTIMG_OFF 0ull
#define XA_OFF     4718592ull
#define XB_OFF     6488064ull
#define OFFS_OFF   8257536ull
#define ARAW_OFF   8699904ull
#define SPT_OFF    4718592ull
#define ATTNW_OFF  11796480ull
#define SIDX_OFF   12017664ull
#define WBF_OFF    12238848ull

static __device__ __forceinline__ float leaky_f(float v) { return v >= 0.f ? v : 0.1f * v; }
static __device__ __forceinline__ u16 f2bf(float f) {
    u32 u = __float_as_uint(f);
    u = (u + 0x7fffu + ((u >> 16) & 1u)) >> 16;
    return (u16)u;
}
static __device__ __forceinline__ float bf2f(u16 v) {
    u32 u = ((u32)v) << 16;
    return __uint_as_float(u);
}

// ---- K0: pack fusion weights to bf16 [d][oc][ic] ----
__global__ __launch_bounds__(256) void k_wprep(const float* __restrict__ fw, u16* __restrict__ wbf) {
    int i = blockIdx.x * 256 + threadIdx.x;      // 9*128*128 = 147456
    int d = i / 16384;
    int r2 = i & 16383;
    int oc = r2 >> 7, ic = r2 & 127;
    wbf[i] = f2bf(fw[((size_t)oc * 128 + ic) * 9 + d]);
}

// ---- K1: extra[:,0:128] = per-16-channel mean of sp at own pixel ----
__global__ __launch_bounds__(256) void k_avgpool(const float* __restrict__ sp,
                                                 float* __restrict__ extra) {
    int idx = blockIdx.x * 256 + threadIdx.x;
    if (idx >= NT * CCH * NPIX) return;
    int pix = idx % NPIX;
    int cc  = (idx / NPIX) % CCH;
    int nt  = idx / (NPIX * CCH);
    const float* p = sp + ((size_t)nt * 2048 + (size_t)cc * 16) * NPIX + pix;
    float s = 0.f;
#pragma unroll
    for (int k = 0; k < 16; k++) s += p[(size_t)k * NPIX];
    extra[((size_t)nt * CIN + cc) * NPIX + pix] = s * 0.0625f;
}

// ---- K2: extra[:,128:256] = gather of pooled field at flow-sampled pixel; [256:258]=flow ----
__global__ __launch_bounds__(256) void k_extra_rest(const float* __restrict__ flow,
                                                    float* __restrict__ extra) {
    int idx = blockIdx.x * 256 + threadIdx.x;
    if (idx >= NT * 130 * NPIX) return;
    int pix = idx % NPIX;
    int cc  = (idx / NPIX) % 130;
    int nt  = idx / (NPIX * 130);
    float fx = flow[((size_t)nt * 2 + 0) * NPIX + pix];
    float fy = flow[((size_t)nt * 2 + 1) * NPIX + pix];
    if (cc >= 128) {
        extra[((size_t)nt * CIN + 256 + (cc - 128)) * NPIX + pix] = (cc == 128) ? fx : fy;
        return;
    }
    int x = pix % WSB, y = pix / WSB;
    float locx = fx + (float)x;
    float locy = fy + (float)y;
    float gfx = 2.0f * locx / 47.0f - 1.0f;
    float gfy = 2.0f * locy / 47.0f - 1.0f;
    float rx = rintf(((gfx + 1.0f) * 0.5f) * 47.0f);
    float ry = rintf(((gfy + 1.0f) * 0.5f) * 47.0f);
    bool valid = (rx >= 0.f) && (rx <= 47.f) && (ry >= 0.f) && (ry <= 47.f);
    int sx = (int)fminf(fmaxf(rx, 0.f), 47.f);
    int sy = (int)fminf(fmaxf(ry, 0.f), 47.f);
    float v = valid ? extra[((size_t)nt * CIN + cc) * NPIX + sy * WSB + sx] : 0.f;
    extra[((size_t)nt * CIN + 128 + cc) * NPIX + pix] = v;
}

// ---- K3: 1x1 conv 258->64 + leaky, both nets (z = net*4+ocg) ----
__global__ __launch_bounds__(256) void k_conv1x1_l0(const float* __restrict__ extra,
                                                    const float* __restrict__ w_so, const float* __restrict__ b_so,
                                                    const float* __restrict__ w_aw, const float* __restrict__ b_aw,
                                                    float* __restrict__ xa) {
    __shared__ float ws_[16 * CIN];
    int tile = blockIdx.x;
    int nt   = blockIdx.y;
    int z    = blockIdx.z;
    int net = z >> 2, ocg = z & 3;
    const float* wsel = net ? w_aw : w_so;
    const float* bsel = net ? b_aw : b_so;
    for (int i = threadIdx.x; i < 16 * CIN; i += 256)
        ws_[i] = wsel[(size_t)(ocg * 16) * CIN + i];
    __syncthreads();
    int pix = tile * 256 + threadIdx.x;
    float acc[16];
#pragma unroll
    for (int o = 0; o < 16; o++) acc[o] = bsel[ocg * 16 + o];
    const float* in = extra + (size_t)nt * CIN * NPIX + pix;
    for (int ci = 0; ci < CIN; ci++) {
        float v = in[(size_t)ci * NPIX];
#pragma unroll
        for (int o = 0; o < 16; o++) acc[o] = fmaf(ws_[o * CIN + ci], v, acc[o]);
    }
    float* op = xa + (((size_t)net * NT + nt) * 64 + ocg * 16) * NPIX + pix;
#pragma unroll
    for (int o = 0; o < 16; o++) op[(size_t)o * NPIX] = leaky_f(acc[o]);
}

// ---- K4: 3x3 conv 64->64 pad1 + leaky, both nets ----
__global__ __launch_bounds__(256) void k_conv3x3(const float* __restrict__ xin,
                                                 const float* __restrict__ w_so, const float* __restrict__ b_so,
                                                 const float* __restrict__ w_aw, const float* __restrict__ b_aw,
                                                 float* __restrict__ xout) {
    __shared__ float tile[18][19];
    int tid = threadIdx.x;
    int tx = tid & 15, ty = tid >> 4;
    int tileid = blockIdx.x;
    int tx0 = (tileid % 3) * 16, ty0 = (tileid / 3) * 16;
    int nt = blockIdx.y;
    int z = blockIdx.z;
    int net = z >> 2, ocg = z & 3;
    const float* w = net ? w_aw : w_so;
    const float* b = net ? b_aw : b_so;
    const float* in = xin + ((size_t)net * NT + nt) * 64 * NPIX;
    float acc[16];
#pragma unroll
    for (int o = 0; o < 16; o++) acc[o] = b[ocg * 16 + o];
    for (int ic = 0; ic < 64; ic++) {
        for (int i = tid; i < 18 * 18; i += 256) {
            int iy = i / 18, ix = i % 18;
            int gy = ty0 + iy - 1, gx = tx0 + ix - 1;
            float v = 0.f;
            if (gy >= 0 && gy < HS && gx >= 0 && gx < WSB)
                v = in[(size_t)ic * NPIX + gy * WSB + gx];
            tile[iy][ix] = v;
        }
        __syncthreads();
        float pv[3][3];
#pragma unroll
        for (int dy = 0; dy < 3; dy++)
#pragma unroll
            for (int dx = 0; dx < 3; dx++)
                pv[dy][dx] = tile[ty + dy][tx + dx];
        const float* wp = w + ((size_t)(ocg * 16) * 64 + ic) * 9;
#pragma unroll
        for (int o = 0; o < 16; o++)
#pragma unroll
            for (int tap = 0; tap < 9; tap++)
                acc[o] = fmaf(wp[(size_t)o * 64 * 9 + tap], pv[tap / 3][tap % 3], acc[o]);
        __syncthreads();
    }
    int pix = (ty0 + ty) * WSB + (tx0 + tx);
    float* op = xout + (((size_t)net * NT + nt) * 64 + ocg * 16) * NPIX + pix;
#pragma unroll
    for (int o = 0; o < 16; o++) op[(size_t)o * NPIX] = leaky_f(acc[o]);
}

// ---- K5: final 1x1 convs ----
__global__ __launch_bounds__(256) void k_conv1x1_l3(const float* __restrict__ xin,
                                                    const float* __restrict__ w_so, const float* __restrict__ b_so,
                                                    const float* __restrict__ w_aw, const float* __restrict__ b_aw,
                                                    float* __restrict__ offs, float* __restrict__ araw) {
    int pix = blockIdx.x * 256 + threadIdx.x;
    int nt = blockIdx.y;
    int net = blockIdx.z;
    const float* in = xin + ((size_t)net * NT + nt) * 64 * NPIX + pix;
    if (net == 0) {
        float acc[32];
#pragma unroll
        for (int o = 0; o < 32; o++) acc[o] = b_so[o];
        for (int ci = 0; ci < 64; ci++) {
            float v = in[(size_t)ci * NPIX];
#pragma unroll
            for (int o = 0; o < 32; o++) acc[o] = fmaf(w_so[o * 64 + ci], v, acc[o]);
        }
#pragma unroll
        for (int o = 0; o < 32; o++) offs[((size_t)nt * 32 + o) * NPIX + pix] = acc[o];
    } else {
        float acc[16];
#pragma unroll
        for (int o = 0; o < 16; o++) acc[o] = b_aw[o];
        for (int ci = 0; ci < 64; ci++) {
            float v = in[(size_t)ci * NPIX];
#pragma unroll
            for (int o = 0; o < 16; o++) acc[o] = fmaf(w_aw[o * 64 + ci], v, acc[o]);
        }
#pragma unroll
        for (int o = 0; o < 16; o++) araw[((size_t)nt * 16 + o) * NPIX + pix] = acc[o];
    }
}

// ---- K6: softmax over 12 (t,p) + sample-index precompute ----
__global__ __launch_bounds__(256) void k_softmax_idx(const float* __restrict__ araw,
                                                     const float* __restrict__ offs,
                                                     const float* __restrict__ flow,
                                                     float* __restrict__ attnw, int* __restrict__ sidx) {
    int idx = blockIdx.x * 256 + threadIdx.x;
    if (idx >= 2 * 4 * NPIX) return;
    int pix  = idx % NPIX;
    int head = (idx / NPIX) & 3;
    int n    = idx / (NPIX * 4);
    int x = pix % WSB, y = pix / WSB;
    float a[12];
#pragma unroll
    for (int t = 0; t < 3; t++)
#pragma unroll
        for (int p = 0; p < 4; p++)
            a[t * 4 + p] = araw[(((size_t)(n * 3 + t)) * 16 + head * 4 + p) * NPIX + pix];
    float mx = a[0];
#pragma unroll
    for (int k = 1; k < 12; k++) mx = fmaxf(mx, a[k]);
    float ssum = 0.f;
#pragma unroll
    for (int k = 0; k < 12; k++) { a[k] = expf(a[k] - mx); ssum += a[k]; }
    float inv = 1.0f / ssum;
#pragma unroll
    for (int t = 0; t < 3; t++) {
        int nt = n * 3 + t;
        float fx = flow[((size_t)nt * 2 + 0) * NPIX + pix];
        float fy = flow[((size_t)nt * 2 + 1) * NPIX + pix];
        float locx = fx + (float)x;
        float locy = fy + (float)y;
#pragma unroll
        for (int p = 0; p < 4; p++) {
            int hp = head * 4 + p;
            float gx_ = locx + offs[(((size_t)nt) * 32 + hp * 2 + 0) * NPIX + pix];
            float gy_ = locy + offs[(((size_t)nt) * 32 + hp * 2 + 1) * NPIX + pix];
            float ngx = 2.0f * gx_ / 48.0f - 1.0f;
            float ngy = 2.0f * gy_ / 48.0f - 1.0f;
            float rx = rintf(((ngx + 1.0f) * 0.5f) * 47.0f);
            float ry = rintf(((ngy + 1.0f) * 0.5f) * 47.0f);
            bool valid = (rx >= 0.f) && (rx <= 47.f) && (ry >= 0.f) && (ry <= 47.f);
            int sx = (int)fminf(fmaxf(rx, 0.f), 47.f);
            int sy = (int)fminf(fmaxf(ry, 0.f), 47.f);
            int k = t * 4 + p;
            attnw[(size_t)idx * 12 + k] = valid ? a[k] * inv : 0.f;
            sidx[(size_t)idx * 12 + k]  = sy * WSB + sx;
        }
    }
}

// ---- K6.5: per-n transpose sp[nt][2048][2304] f32 -> spT[t][pix][2048] bf16 ----
__global__ __launch_bounds__(256) void k_transpose(const float* __restrict__ sp,
                                                   u16* __restrict__ spT, int n) {
    __shared__ float tile[64][65];
    int tid = threadIdx.x;
    int pix0 = blockIdx.x * 64;    // 36 tiles
    int ch0  = blockIdx.y * 64;    // 32 tiles
    int tl   = blockIdx.z;         // 0..2 (t within n)
    int nt = n * 3 + tl;
    const float* base = sp + ((size_t)nt * 2048 + ch0) * NPIX + pix0;
#pragma unroll
    for (int k = 0; k < 16; k++) {
        int row = k * 4 + (tid >> 6);
        int col = tid & 63;
        tile[row][col] = base[(size_t)row * NPIX + col];
    }
    __syncthreads();
#pragma unroll
    for (int k = 0; k < 2; k++) {
        int task = k * 256 + tid;
        int pl = task >> 3;           // pix_local 0..63
        int c0 = (task & 7) * 8;      // ch chunk
        u16 pk[8];
#pragma unroll
        for (int j = 0; j < 8; j++) pk[j] = f2bf(tile[c0 + j][pl]);
        *reinterpret_cast<int4*>(spT + ((size_t)tl * NPIX + pix0 + pl) * 2048 + ch0 + c0) =
            *reinterpret_cast<const int4*>(pk);
    }
}

// ---- K7: coalesced 12-term gather from spT -> bf16 NHWC outimg (one wave per head) ----
__global__ __launch_bounds__(256) void k_gather2(const u16* __restrict__ spT,
                                                 const float* __restrict__ attnw,
                                                 const int* __restrict__ sidx,
                                                 u16* __restrict__ outimg, int n) {
    __shared__ u16 sArr[2048 + 128];
    int tid = threadIdx.x;
    int pix = blockIdx.x;
    int y = pix / WSB, x = pix % WSB;
    int h = tid >> 6;      // head = wave id
    int lane = tid & 63;
    size_t ab = ((size_t)(n * 4 + h) * NPIX + pix) * 12;
    float acc[8] = {};
#pragma unroll
    for (int t = 0; t < 3; t++) {
#pragma unroll
        for (int p = 0; p < 4; p++) {
            int k = t * 4 + p;
            float w = attnw[ab + k];
            int idx = sidx[ab + k];
            bf16x8 v = *reinterpret_cast<const bf16x8*>(
                spT + ((size_t)t * NPIX + idx) * 2048 + h * 512 + lane * 8);
#pragma unroll
            for (int j = 0; j < 8; j++)
                acc[j] = fmaf(w, bf2f((u16)v[j]), acc[j]);
        }
    }
    // stage to LDS (padded: idx = ch + ch/16)
    int c0 = h * 512 + lane * 8;
    int si = c0 + (c0 >> 4);
    u16 pk[8];
#pragma unroll
    for (int j = 0; j < 8; j++) pk[j] = f2bf(acc[j]);
    *reinterpret_cast<int4*>(&sArr[si]) = *reinterpret_cast<const int4*>(pk);
    __syncthreads();
    // coalesced NHWC write: thread covers opix = tid>>4, oc0 = (tid&15)*8
    int opix = tid >> 4;
    int oc0 = (tid & 15) * 8;
    u16 ov[8];
#pragma unroll
    for (int j = 0; j < 8; j++) {
        int oc = oc0 + j;
        int ch = (oc >> 5) * 512 + (oc & 31) * 16 + opix;
        ov[j] = sArr[ch + (ch >> 4)];
    }
    int hq = y * 4 + (opix >> 2);
    int wq = x * 4 + (opix & 3);
    *reinterpret_cast<int4*>(outimg + (((size_t)(n * HH + hq) * WW + wq) << 7) + oc0) =
        *reinterpret_cast<const int4*>(ov);
}

// ---- K8: fusion 3x3 conv 128->128 via bf16 MFMA implicit GEMM ----
__global__ __launch_bounds__(256, 2) void k_fusion_mfma(const u16* __restrict__ img,   // bf16 NHWC
                                                        const u16* __restrict__ wbf,   // bf16 [9][oc][ic]
                                                        const float* __restrict__ bias,
                                                        const float* __restrict__ anchor,
                                                        float* __restrict__ out) {
    __shared__ __align__(16) u16 lds_in[180 * 128];
    __shared__ __align__(16) u16 lds_w[128 * 128];

    const int tid = threadIdx.x;
    const int px0 = blockIdx.x * 16;
    const int py0 = blockIdx.y * 8;
    const int nb  = blockIdx.z;
    const int lane = tid & 63;
    const int wave = tid >> 6;
    const int wm = wave >> 1, wn = wave & 1;
    const int r = lane & 15, g = lane >> 4;

    char* lin_b = reinterpret_cast<char*>(lds_in);
    char* lw_b  = reinterpret_cast<char*>(lds_w);

    for (int i = tid; i < 180 * 16; i += 256) {
        int p = i >> 4, c16 = i & 15;
        int hy = p / 18, hx = p % 18;
        int gy = py0 + hy - 1, gx = px0 + hx - 1;
        int4 v = make_int4(0, 0, 0, 0);
        if (gy >= 0 && gy < HH && gx >= 0 && gx < WW)
            v = *reinterpret_cast<const int4*>(img + (((size_t)(nb * HH + gy) * WW + gx) << 7) + (c16 << 3));
        *reinterpret_cast<int4*>(lin_b + p * 256 + (((c16 ^ (p & 7)) << 4))) = v;
    }

    int pym[4], pxm[4], ocn[4];
#pragma unroll
    for (int m = 0; m < 4; m++) { int p = wm * 64 + m * 16 + r; pym[m] = p >> 4; pxm[m] = p & 15; }
#pragma unroll
    for (int n = 0; n < 4; n++) ocn[n] = wn * 64 + n * 16 + r;

    f32x4 acc[4][4] = {};
    int4 wr[8];
#pragma unroll
    for (int q = 0; q < 8; q++)
        wr[q] = *reinterpret_cast<const int4*>(wbf + (size_t)(tid + q * 256) * 8);

    for (int d = 0; d < 9; d++) {
#pragma unroll
        for (int q = 0; q < 8; q++) {
            int j = tid + q * 256;
            int oc = j >> 4, c16 = j & 15;
            *reinterpret_cast<int4*>(lw_b + oc * 256 + (((c16 ^ (oc & 7)) << 4))) = wr[q];
        }
        __syncthreads();
        if (d < 8) {
#pragma unroll
            for (int q = 0; q < 8; q++)
                wr[q] = *reinterpret_cast<const int4*>(wbf + (size_t)(d + 1) * 16384 + (size_t)(tid + q * 256) * 8);
        }
        int dy = d / 3, dx = d % 3;
#pragma unroll
        for (int kc = 0; kc < 4; kc++) {
            int c16 = kc * 4 + g;
            bf16x8 a[4], b[4];
#pragma unroll
            for (int m = 0; m < 4; m++) {
                int hp = (pym[m] + dy) * 18 + (pxm[m] + dx);
                a[m] = *reinterpret_cast<const bf16x8*>(lin_b + hp * 256 + (((c16 ^ (hp & 7)) << 4)));
            }
#pragma unroll
            for (int n = 0; n < 4; n++)
                b[n] = *reinterpret_cast<const bf16x8*>(lw_b + ocn[n] * 256 + (((c16 ^ (ocn[n] & 7)) << 4)));
#pragma unroll
            for (int m = 0; m < 4; m++)
#pragma unroll
                for (int n = 0; n < 4; n++)
                    acc[m][n] = __builtin_amdgcn_mfma_f32_16x16x32_bf16(a[m], b[n], acc[m][n], 0, 0, 0);
        }
        __syncthreads();
    }

    float* buf = reinterpret_cast<float*>(lds_w);
    for (int mg = 0; mg < 8; mg++) {
        if (wm == (mg >> 2)) {
            int m = mg & 3;
#pragma unroll
            for (int n = 0; n < 4; n++) {
                int oc = ocn[n];
#pragma unroll
                for (int reg = 0; reg < 4; reg++)
                    buf[oc * 17 + g * 4 + reg] = acc[m][n][reg];
            }
        }
        __syncthreads();
        {
            int pxl = tid & 15;
            int ocq = tid >> 4;
            int gy = py0 + mg;
#pragma unroll
            for (int q = 0; q < 8; q++) {
                int oc = ocq + q * 16;
                float v = buf[oc * 17 + pxl];
                size_t oa = ((size_t)(nb * CCH + oc)) * (HH * WW) + (size_t)gy * WW + px0 + pxl;
                out[oa] = v + bias[oc] + anchor[oa];
            }
        }
        __syncthreads();
    }
}

extern "C" void kernel_launch(void* const* d_in, const int* in_sizes, int n_in,
                              void* d_out, int out_size, void* d_ws, size_t ws_size,
                              hipStream_t stream) {
    (void)in_sizes; (void)n_in; (void)out_size; (void)ws_size;
    const float* anchor = (const float*)d_in[1];
    const float* sp     = (const float*)d_in[2];
    const float* flow   = (const float*)d_in[3];
    const float* so_w0 = (const float*)d_in[4];  const float* so_b0 = (const float*)d_in[5];
    const float* so_w1 = (const float*)d_in[6];  const float* so_b1 = (const float*)d_in[7];
    const float* so_w2 = (const float*)d_in[8];  const float* so_b2 = (const float*)d_in[9];
    const float* so_w3 = (const float*)d_in[10]; const float* so_b3 = (const float*)d_in[11];
    const float* aw_w0 = (const float*)d_in[12]; const float* aw_b0 = (const float*)d_in[13];
    const float* aw_w1 = (const float*)d_in[14]; const float* aw_b1 = (const float*)d_in[15];
    const float* aw_w2 = (const float*)d_in[16]; const float* aw_b2 = (const float*)d_in[17];
    const float* aw_w3 = (const float*)d_in[18]; const float* aw_b3 = (const float*)d_in[19];
    const float* fw    = (const float*)d_in[20]; const float* fb    = (const float*)d_in[21];

    float* ws     = (float*)d_ws;
    float* extra  = ws + EXTRA_OFF;
    float* xa     = ws + XA_OFF;
    float* xb     = ws + XB_OFF;
    float* offs   = ws + OFFS_OFF;
    float* araw   = ws + ARAW_OFF;
    float* attnw  = ws + ATTNW_OFF;
    int*   sidx   = (int*)(ws + SIDX_OFF);
    u16*   wbf    = (u16*)(ws + WBF_OFF);
    u16*   spT    = (u16*)(ws + SPT_OFF);
    u16*   outimg = (u16*)(ws + OUTIMG_OFF);
    float* outp   = (float*)d_out;

    k_wprep<<<dim3(576), 256, 0, stream>>>(fw, wbf);
    k_avgpool<<<dim3((NT * CCH * NPIX + 255) / 256), 256, 0, stream>>>(sp, extra);
    k_extra_rest<<<dim3((NT * 130 * NPIX + 255) / 256), 256, 0, stream>>>(flow, extra);
    k_conv1x1_l0<<<dim3(9, 6, 8), 256, 0, stream>>>(extra, so_w0, so_b0, aw_w0, aw_b0, xa);
    k_conv3x3<<<dim3(9, 6, 8), 256, 0, stream>>>(xa, so_w1, so_b1, aw_w1, aw_b1, xb);
    k_conv3x3<<<dim3(9, 6, 8), 256, 0, stream>>>(xb, so_w2, so_b2, aw_w2, aw_b2, xa);
    k_conv1x1_l3<<<dim3(9, 6, 2), 256, 0, stream>>>(xa, so_w3, so_b3, aw_w3, aw_b3, offs, araw);
    k_softmax_idx<<<dim3((2 * 4 * NPIX + 255) / 256), 256, 0, stream>>>(araw, offs, flow, attnw, sidx);
    for (int n = 0; n < 2; n++) {
        k_transpose<<<dim3(36, 32, 3), 256, 0, stream>>>(sp, spT, n);
        k_gather2<<<dim3(NPIX), 256, 0, stream>>>(spT, attnw, sidx, outimg, n);
    }
    k_fusion_mfma<<<dim3(WW / 16, HH / 8, 2), 256, 0, stream>>>(outimg, wbf, fb, anchor, outp);
}

// Round 4
// 460.652 us; speedup vs baseline: 2.3704x; 1.0202x over previous
//
#include <hip/hip_runtime.h>

typedef unsigned short u16;
typedef unsigned int u32;
typedef __attribute__((ext_vector_type(8))) short bf16x8;
typedef __attribute__((ext_vector_type(4))) float f32x4;

// Problem constants (fixed shapes from setup_inputs)
#define HS   48
#define WSB  48
#define NPIX 2304        // 48*48
#define CCH  128         // c
#define NT   6           // n*t
#define CIN  258         // 2c+2
#define HH   192
#define WW   192

// ws layout in f32 slots (see R3 comment; unchanged)
#define EXTRA_OFF  0ull
#define OUTIMG_OFF 0ull
#define XA_OFF     4718592ull
#define XB_OFF     6488064ull
#define OFFS_OFF   8257536ull
#define ARAW_OFF   8699904ull
#define SPT_OFF    4718592ull
#define ATTNW_OFF  11796480ull
#define SIDX_OFF   12017664ull
#define WBF_OFF    12238848ull

static __device__ __forceinline__ float leaky_f(float v) { return v >= 0.f ? v : 0.1f * v; }
static __device__ __forceinline__ u16 f2bf(float f) {
    u32 u = __float_as_uint(f);
    u = (u + 0x7fffu + ((u >> 16) & 1u)) >> 16;
    return (u16)u;
}
static __device__ __forceinline__ float bf2f(u16 v) {
    u32 u = ((u32)v) << 16;
    return __uint_as_float(u);
}

// ---- K0: pack fusion weights to bf16 [d][oc][ic] ----
__global__ __launch_bounds__(256) void k_wprep(const float* __restrict__ fw, u16* __restrict__ wbf) {
    int i = blockIdx.x * 256 + threadIdx.x;      // 9*128*128 = 147456
    int d = i / 16384;
    int r2 = i & 16383;
    int oc = r2 >> 7, ic = r2 & 127;
    wbf[i] = f2bf(fw[((size_t)oc * 128 + ic) * 9 + d]);
}

// ---- K1: extra[:,0:128] = per-16-channel mean of sp at own pixel ----
__global__ __launch_bounds__(256) void k_avgpool(const float* __restrict__ sp,
                                                 float* __restrict__ extra) {
    int idx = blockIdx.x * 256 + threadIdx.x;
    if (idx >= NT * CCH * NPIX) return;
    int pix = idx % NPIX;
    int cc  = (idx / NPIX) % CCH;
    int nt  = idx / (NPIX * CCH);
    const float* p = sp + ((size_t)nt * 2048 + (size_t)cc * 16) * NPIX + pix;
    float s = 0.f;
#pragma unroll
    for (int k = 0; k < 16; k++) s += p[(size_t)k * NPIX];
    extra[((size_t)nt * CIN + cc) * NPIX + pix] = s * 0.0625f;
}

// ---- K2: extra[:,128:256] = gather of pooled field at flow-sampled pixel; [256:258]=flow ----
__global__ __launch_bounds__(256) void k_extra_rest(const float* __restrict__ flow,
                                                    float* __restrict__ extra) {
    int idx = blockIdx.x * 256 + threadIdx.x;
    if (idx >= NT * 130 * NPIX) return;
    int pix = idx % NPIX;
    int cc  = (idx / NPIX) % 130;
    int nt  = idx / (NPIX * 130);
    float fx = flow[((size_t)nt * 2 + 0) * NPIX + pix];
    float fy = flow[((size_t)nt * 2 + 1) * NPIX + pix];
    if (cc >= 128) {
        extra[((size_t)nt * CIN + 256 + (cc - 128)) * NPIX + pix] = (cc == 128) ? fx : fy;
        return;
    }
    int x = pix % WSB, y = pix / WSB;
    float locx = fx + (float)x;
    float locy = fy + (float)y;
    float gfx = 2.0f * locx / 47.0f - 1.0f;
    float gfy = 2.0f * locy / 47.0f - 1.0f;
    float rx = rintf(((gfx + 1.0f) * 0.5f) * 47.0f);
    float ry = rintf(((gfy + 1.0f) * 0.5f) * 47.0f);
    bool valid = (rx >= 0.f) && (rx <= 47.f) && (ry >= 0.f) && (ry <= 47.f);
    int sx = (int)fminf(fmaxf(rx, 0.f), 47.f);
    int sy = (int)fminf(fmaxf(ry, 0.f), 47.f);
    float v = valid ? extra[((size_t)nt * CIN + cc) * NPIX + sy * WSB + sx] : 0.f;
    extra[((size_t)nt * CIN + 128 + cc) * NPIX + pix] = v;
}

// ---- K3: 1x1 conv 258->64 + leaky, both nets (z = net*4+ocg) ----
__global__ __launch_bounds__(256) void k_conv1x1_l0(const float* __restrict__ extra,
                                                    const float* __restrict__ w_so, const float* __restrict__ b_so,
                                                    const float* __restrict__ w_aw, const float* __restrict__ b_aw,
                                                    float* __restrict__ xa) {
    __shared__ float ws_[16 * CIN];
    int tile = blockIdx.x;
    int nt   = blockIdx.y;
    int z    = blockIdx.z;
    int net = z >> 2, ocg = z & 3;
    const float* wsel = net ? w_aw : w_so;
    const float* bsel = net ? b_aw : b_so;
    for (int i = threadIdx.x; i < 16 * CIN; i += 256)
        ws_[i] = wsel[(size_t)(ocg * 16) * CIN + i];
    __syncthreads();
    int pix = tile * 256 + threadIdx.x;
    float acc[16];
#pragma unroll
    for (int o = 0; o < 16; o++) acc[o] = bsel[ocg * 16 + o];
    const float* in = extra + (size_t)nt * CIN * NPIX + pix;
    for (int ci = 0; ci < CIN; ci++) {
        float v = in[(size_t)ci * NPIX];
#pragma unroll
        for (int o = 0; o < 16; o++) acc[o] = fmaf(ws_[o * CIN + ci], v, acc[o]);
    }
    float* op = xa + (((size_t)net * NT + nt) * 64 + ocg * 16) * NPIX + pix;
#pragma unroll
    for (int o = 0; o < 16; o++) op[(size_t)o * NPIX] = leaky_f(acc[o]);
}

// ---- K4: 3x3 conv 64->64 pad1 + leaky, both nets (restructured R4) ----
// grid (9, 6, 16): z = net*8 + ocg (8 oc per group). 864 blocks.
// LDS: weights [8oc][64ic][9] staged once (18.4 KB) + input tile chunk
// [16ic][18][19] (21.9 KB). 8 barriers total; 1152 FMA between barriers.
__global__ __launch_bounds__(256) void k_conv3x3(const float* __restrict__ xin,
                                                 const float* __restrict__ w_so, const float* __restrict__ b_so,
                                                 const float* __restrict__ w_aw, const float* __restrict__ b_aw,
                                                 float* __restrict__ xout) {
    __shared__ float wlds[8 * 64 * 9];
    __shared__ float tile[16][18][19];
    int tid = threadIdx.x;
    int tx = tid & 15, ty = tid >> 4;
    int tileid = blockIdx.x;
    int tx0 = (tileid % 3) * 16, ty0 = (tileid / 3) * 16;
    int nt = blockIdx.y;
    int z = blockIdx.z;
    int net = z >> 3, ocg = z & 7;
    const float* w = net ? w_aw : w_so;
    const float* b = net ? b_aw : b_so;
    const float* in = xin + ((size_t)net * NT + nt) * 64 * NPIX;

    // stage this group's weight slab (contiguous 4608 floats), coalesced
    const float* wbase = w + (size_t)(ocg * 8) * 64 * 9;
    for (int i = tid; i < 4608; i += 256) wlds[i] = wbase[i];

    float acc[8];
#pragma unroll
    for (int o = 0; o < 8; o++) acc[o] = b[ocg * 8 + o];

    for (int c0 = 0; c0 < 64; c0 += 16) {
        __syncthreads();   // prior compute done (and first iter: weights staged)
        for (int i = tid; i < 16 * 324; i += 256) {
            int ic = i / 324;
            int r = i - ic * 324;
            int iy = r / 18, ix = r - iy * 18;
            int gy = ty0 + iy - 1, gx = tx0 + ix - 1;
            float v = 0.f;
            if (gy >= 0 && gy < HS && gx >= 0 && gx < WSB)
                v = in[(size_t)(c0 + ic) * NPIX + gy * WSB + gx];
            tile[ic][iy][ix] = v;
        }
        __syncthreads();
#pragma unroll 2
        for (int ic = 0; ic < 16; ic++) {
            float pv[3][3];
#pragma unroll
            for (int dy = 0; dy < 3; dy++)
#pragma unroll
                for (int dx = 0; dx < 3; dx++)
                    pv[dy][dx] = tile[ic][ty + dy][tx + dx];
            const int wi = (c0 + ic) * 9;
#pragma unroll
            for (int o = 0; o < 8; o++)
#pragma unroll
                for (int tap = 0; tap < 9; tap++)
                    acc[o] = fmaf(wlds[o * 576 + wi + tap], pv[tap / 3][tap % 3], acc[o]);
        }
    }

    int pix = (ty0 + ty) * WSB + (tx0 + tx);
    float* op = xout + (((size_t)net * NT + nt) * 64 + ocg * 8) * NPIX + pix;
#pragma unroll
    for (int o = 0; o < 8; o++) op[(size_t)o * NPIX] = leaky_f(acc[o]);
}

// ---- K5: final 1x1 convs ----
__global__ __launch_bounds__(256) void k_conv1x1_l3(const float* __restrict__ xin,
                                                    const float* __restrict__ w_so, const float* __restrict__ b_so,
                                                    const float* __restrict__ w_aw, const float* __restrict__ b_aw,
                                                    float* __restrict__ offs, float* __restrict__ araw) {
    int pix = blockIdx.x * 256 + threadIdx.x;
    int nt = blockIdx.y;
    int net = blockIdx.z;
    const float* in = xin + ((size_t)net * NT + nt) * 64 * NPIX + pix;
    if (net == 0) {
        float acc[32];
#pragma unroll
        for (int o = 0; o < 32; o++) acc[o] = b_so[o];
        for (int ci = 0; ci < 64; ci++) {
            float v = in[(size_t)ci * NPIX];
#pragma unroll
            for (int o = 0; o < 32; o++) acc[o] = fmaf(w_so[o * 64 + ci], v, acc[o]);
        }
#pragma unroll
        for (int o = 0; o < 32; o++) offs[((size_t)nt * 32 + o) * NPIX + pix] = acc[o];
    } else {
        float acc[16];
#pragma unroll
        for (int o = 0; o < 16; o++) acc[o] = b_aw[o];
        for (int ci = 0; ci < 64; ci++) {
            float v = in[(size_t)ci * NPIX];
#pragma unroll
            for (int o = 0; o < 16; o++) acc[o] = fmaf(w_aw[o * 64 + ci], v, acc[o]);
        }
#pragma unroll
        for (int o = 0; o < 16; o++) araw[((size_t)nt * 16 + o) * NPIX + pix] = acc[o];
    }
}

// ---- K6: softmax over 12 (t,p) + sample-index precompute ----
__global__ __launch_bounds__(256) void k_softmax_idx(const float* __restrict__ araw,
                                                     const float* __restrict__ offs,
                                                     const float* __restrict__ flow,
                                                     float* __restrict__ attnw, int* __restrict__ sidx) {
    int idx = blockIdx.x * 256 + threadIdx.x;
    if (idx >= 2 * 4 * NPIX) return;
    int pix  = idx % NPIX;
    int head = (idx / NPIX) & 3;
    int n    = idx / (NPIX * 4);
    int x = pix % WSB, y = pix / WSB;
    float a[12];
#pragma unroll
    for (int t = 0; t < 3; t++)
#pragma unroll
        for (int p = 0; p < 4; p++)
            a[t * 4 + p] = araw[(((size_t)(n * 3 + t)) * 16 + head * 4 + p) * NPIX + pix];
    float mx = a[0];
#pragma unroll
    for (int k = 1; k < 12; k++) mx = fmaxf(mx, a[k]);
    float ssum = 0.f;
#pragma unroll
    for (int k = 0; k < 12; k++) { a[k] = expf(a[k] - mx); ssum += a[k]; }
    float inv = 1.0f / ssum;
#pragma unroll
    for (int t = 0; t < 3; t++) {
        int nt = n * 3 + t;
        float fx = flow[((size_t)nt * 2 + 0) * NPIX + pix];
        float fy = flow[((size_t)nt * 2 + 1) * NPIX + pix];
        float locx = fx + (float)x;
        float locy = fy + (float)y;
#pragma unroll
        for (int p = 0; p < 4; p++) {
            int hp = head * 4 + p;
            float gx_ = locx + offs[(((size_t)nt) * 32 + hp * 2 + 0) * NPIX + pix];
            float gy_ = locy + offs[(((size_t)nt) * 32 + hp * 2 + 1) * NPIX + pix];
            float ngx = 2.0f * gx_ / 48.0f - 1.0f;
            float ngy = 2.0f * gy_ / 48.0f - 1.0f;
            float rx = rintf(((ngx + 1.0f) * 0.5f) * 47.0f);
            float ry = rintf(((ngy + 1.0f) * 0.5f) * 47.0f);
            bool valid = (rx >= 0.f) && (rx <= 47.f) && (ry >= 0.f) && (ry <= 47.f);
            int sx = (int)fminf(fmaxf(rx, 0.f), 47.f);
            int sy = (int)fminf(fmaxf(ry, 0.f), 47.f);
            int k = t * 4 + p;
            attnw[(size_t)idx * 12 + k] = valid ? a[k] * inv : 0.f;
            sidx[(size_t)idx * 12 + k]  = sy * WSB + sx;
        }
    }
}

// ---- K6.5: per-n transpose sp[nt][2048][2304] f32 -> spT[t][pix][2048] bf16 ----
__global__ __launch_bounds__(256) void k_transpose(const float* __restrict__ sp,
                                                   u16* __restrict__ spT, int n) {
    __shared__ float tile[64][65];
    int tid = threadIdx.x;
    int pix0 = blockIdx.x * 64;    // 36 tiles
    int ch0  = blockIdx.y * 64;    // 32 tiles
    int tl   = blockIdx.z;         // 0..2 (t within n)
    int nt = n * 3 + tl;
    const float* base = sp + ((size_t)nt * 2048 + ch0) * NPIX + pix0;
#pragma unroll
    for (int k = 0; k < 16; k++) {
        int row = k * 4 + (tid >> 6);
        int col = tid & 63;
        tile[row][col] = base[(size_t)row * NPIX + col];
    }
    __syncthreads();
#pragma unroll
    for (int k = 0; k < 2; k++) {
        int task = k * 256 + tid;
        int pl = task >> 3;           // pix_local 0..63
        int c0 = (task & 7) * 8;      // ch chunk
        u16 pk[8];
#pragma unroll
        for (int j = 0; j < 8; j++) pk[j] = f2bf(tile[c0 + j][pl]);
        *reinterpret_cast<int4*>(spT + ((size_t)tl * NPIX + pix0 + pl) * 2048 + ch0 + c0) =
            *reinterpret_cast<const int4*>(pk);
    }
}

// ---- K7: coalesced 12-term gather from spT -> bf16 NHWC outimg (one wave per head) ----
__global__ __launch_bounds__(256) void k_gather2(const u16* __restrict__ spT,
                                                 const float* __restrict__ attnw,
                                                 const int* __restrict__ sidx,
                                                 u16* __restrict__ outimg, int n) {
    __shared__ u16 sArr[2048 + 128];
    int tid = threadIdx.x;
    int pix = blockIdx.x;
    int y = pix / WSB, x = pix % WSB;
    int h = tid >> 6;      // head = wave id
    int lane = tid & 63;
    size_t ab = ((size_t)(n * 4 + h) * NPIX + pix) * 12;
    float acc[8] = {};
#pragma unroll
    for (int t = 0; t < 3; t++) {
#pragma unroll
        for (int p = 0; p < 4; p++) {
            int k = t * 4 + p;
            float w = attnw[ab + k];
            int idx = sidx[ab + k];
            bf16x8 v = *reinterpret_cast<const bf16x8*>(
                spT + ((size_t)t * NPIX + idx) * 2048 + h * 512 + lane * 8);
#pragma unroll
            for (int j = 0; j < 8; j++)
                acc[j] = fmaf(w, bf2f((u16)v[j]), acc[j]);
        }
    }
    int c0 = h * 512 + lane * 8;
    int si = c0 + (c0 >> 4);
    u16 pk[8];
#pragma unroll
    for (int j = 0; j < 8; j++) pk[j] = f2bf(acc[j]);
    *reinterpret_cast<int4*>(&sArr[si]) = *reinterpret_cast<const int4*>(pk);
    __syncthreads();
    int opix = tid >> 4;
    int oc0 = (tid & 15) * 8;
    u16 ov[8];
#pragma unroll
    for (int j = 0; j < 8; j++) {
        int oc = oc0 + j;
        int ch = (oc >> 5) * 512 + (oc & 31) * 16 + opix;
        ov[j] = sArr[ch + (ch >> 4)];
    }
    int hq = y * 4 + (opix >> 2);
    int wq = x * 4 + (opix & 3);
    *reinterpret_cast<int4*>(outimg + (((size_t)(n * HH + hq) * WW + wq) << 7) + oc0) =
        *reinterpret_cast<const int4*>(ov);
}

// ---- K8: fusion 3x3 conv 128->128 via bf16 MFMA implicit GEMM ----
__global__ __launch_bounds__(256, 2) void k_fusion_mfma(const u16* __restrict__ img,   // bf16 NHWC
                                                        const u16* __restrict__ wbf,   // bf16 [9][oc][ic]
                                                        const float* __restrict__ bias,
                                                        const float* __restrict__ anchor,
                                                        float* __restrict__ out) {
    __shared__ __align__(16) u16 lds_in[180 * 128];
    __shared__ __align__(16) u16 lds_w[128 * 128];

    const int tid = threadIdx.x;
    const int px0 = blockIdx.x * 16;
    const int py0 = blockIdx.y * 8;
    const int nb  = blockIdx.z;
    const int lane = tid & 63;
    const int wave = tid >> 6;
    const int wm = wave >> 1, wn = wave & 1;
    const int r = lane & 15, g = lane >> 4;

    char* lin_b = reinterpret_cast<char*>(lds_in);
    char* lw_b  = reinterpret_cast<char*>(lds_w);

    for (int i = tid; i < 180 * 16; i += 256) {
        int p = i >> 4, c16 = i & 15;
        int hy = p / 18, hx = p % 18;
        int gy = py0 + hy - 1, gx = px0 + hx - 1;
        int4 v = make_int4(0, 0, 0, 0);
        if (gy >= 0 && gy < HH && gx >= 0 && gx < WW)
            v = *reinterpret_cast<const int4*>(img + (((size_t)(nb * HH + gy) * WW + gx) << 7) + (c16 << 3));
        *reinterpret_cast<int4*>(lin_b + p * 256 + (((c16 ^ (p & 7)) << 4))) = v;
    }

    int pym[4], pxm[4], ocn[4];
#pragma unroll
    for (int m = 0; m < 4; m++) { int p = wm * 64 + m * 16 + r; pym[m] = p >> 4; pxm[m] = p & 15; }
#pragma unroll
    for (int n = 0; n < 4; n++) ocn[n] = wn * 64 + n * 16 + r;

    f32x4 acc[4][4] = {};
    int4 wr[8];
#pragma unroll
    for (int q = 0; q < 8; q++)
        wr[q] = *reinterpret_cast<const int4*>(wbf + (size_t)(tid + q * 256) * 8);

    for (int d = 0; d < 9; d++) {
#pragma unroll
        for (int q = 0; q < 8; q++) {
            int j = tid + q * 256;
            int oc = j >> 4, c16 = j & 15;
            *reinterpret_cast<int4*>(lw_b + oc * 256 + (((c16 ^ (oc & 7)) << 4))) = wr[q];
        }
        __syncthreads();
        if (d < 8) {
#pragma unroll
            for (int q = 0; q < 8; q++)
                wr[q] = *reinterpret_cast<const int4*>(wbf + (size_t)(d + 1) * 16384 + (size_t)(tid + q * 256) * 8);
        }
        int dy = d / 3, dx = d % 3;
#pragma unroll
        for (int kc = 0; kc < 4; kc++) {
            int c16 = kc * 4 + g;
            bf16x8 a[4], b[4];
#pragma unroll
            for (int m = 0; m < 4; m++) {
                int hp = (pym[m] + dy) * 18 + (pxm[m] + dx);
                a[m] = *reinterpret_cast<const bf16x8*>(lin_b + hp * 256 + (((c16 ^ (hp & 7)) << 4)));
            }
#pragma unroll
            for (int n = 0; n < 4; n++)
                b[n] = *reinterpret_cast<const bf16x8*>(lw_b + ocn[n] * 256 + (((c16 ^ (ocn[n] & 7)) << 4)));
#pragma unroll
            for (int m = 0; m < 4; m++)
#pragma unroll
                for (int n = 0; n < 4; n++)
                    acc[m][n] = __builtin_amdgcn_mfma_f32_16x16x32_bf16(a[m], b[n], acc[m][n], 0, 0, 0);
        }
        __syncthreads();
    }

    float* buf = reinterpret_cast<float*>(lds_w);
    for (int mg = 0; mg < 8; mg++) {
        if (wm == (mg >> 2)) {
            int m = mg & 3;
#pragma unroll
            for (int n = 0; n < 4; n++) {
                int oc = ocn[n];
#pragma unroll
                for (int reg = 0; reg < 4; reg++)
                    buf[oc * 17 + g * 4 + reg] = acc[m][n][reg];
            }
        }
        __syncthreads();
        {
            int pxl = tid & 15;
            int ocq = tid >> 4;
            int gy = py0 + mg;
#pragma unroll
            for (int q = 0; q < 8; q++) {
                int oc = ocq + q * 16;
                float v = buf[oc * 17 + pxl];
                size_t oa = ((size_t)(nb * CCH + oc)) * (HH * WW) + (size_t)gy * WW + px0 + pxl;
                out[oa] = v + bias[oc] + anchor[oa];
            }
        }
        __syncthreads();
    }
}

extern "C" void kernel_launch(void* const* d_in, const int* in_sizes, int n_in,
                              void* d_out, int out_size, void* d_ws, size_t ws_size,
                              hipStream_t stream) {
    (void)in_sizes; (void)n_in; (void)out_size; (void)ws_size;
    const float* anchor = (const float*)d_in[1];
    const float* sp     = (const float*)d_in[2];
    const float* flow   = (const float*)d_in[3];
    const float* so_w0 = (const float*)d_in[4];  const float* so_b0 = (const float*)d_in[5];
    const float* so_w1 = (const float*)d_in[6];  const float* so_b1 = (const float*)d_in[7];
    const float* so_w2 = (const float*)d_in[8];  const float* so_b2 = (const float*)d_in[9];
    const float* so_w3 = (const float*)d_in[10]; const float* so_b3 = (const float*)d_in[11];
    const float* aw_w0 = (const float*)d_in[12]; const float* aw_b0 = (const float*)d_in[13];
    const float* aw_w1 = (const float*)d_in[14]; const float* aw_b1 = (const float*)d_in[15];
    const float* aw_w2 = (const float*)d_in[16]; const float* aw_b2 = (const float*)d_in[17];
    const float* aw_w3 = (const float*)d_in[18]; const float* aw_b3 = (const float*)d_in[19];
    const float* fw    = (const float*)d_in[20]; const float* fb    = (const float*)d_in[21];

    float* ws     = (float*)d_ws;
    float* extra  = ws + EXTRA_OFF;
    float* xa     = ws + XA_OFF;
    float* xb     = ws + XB_OFF;
    float* offs   = ws + OFFS_OFF;
    float* araw   = ws + ARAW_OFF;
    float* attnw  = ws + ATTNW_OFF;
    int*   sidx   = (int*)(ws + SIDX_OFF);
    u16*   wbf    = (u16*)(ws + WBF_OFF);
    u16*   spT    = (u16*)(ws + SPT_OFF);
    u16*   outimg = (u16*)(ws + OUTIMG_OFF);
    float* outp   = (float*)d_out;

    k_wprep<<<dim3(576), 256, 0, stream>>>(fw, wbf);
    k_avgpool<<<dim3((NT * CCH * NPIX + 255) / 256), 256, 0, stream>>>(sp, extra);
    k_extra_rest<<<dim3((NT * 130 * NPIX + 255) / 256), 256, 0, stream>>>(flow, extra);
    k_conv1x1_l0<<<dim3(9, 6, 8), 256, 0, stream>>>(extra, so_w0, so_b0, aw_w0, aw_b0, xa);
    k_conv3x3<<<dim3(9, 6, 16), 256, 0, stream>>>(xa, so_w1, so_b1, aw_w1, aw_b1, xb);
    k_conv3x3<<<dim3(9, 6, 16), 256, 0, stream>>>(xb, so_w2, so_b2, aw_w2, aw_b2, xa);
    k_conv1x1_l3<<<dim3(9, 6, 2), 256, 0, stream>>>(xa, so_w3, so_b3, aw_w3, aw_b3, offs, araw);
    k_softmax_idx<<<dim3((2 * 4 * NPIX + 255) / 256), 256, 0, stream>>>(araw, offs, flow, attnw, sidx);
    for (int n = 0; n < 2; n++) {
        k_transpose<<<dim3(36, 32, 3), 256, 0, stream>>>(sp, spT, n);
        k_gather2<<<dim3(NPIX), 256, 0, stream>>>(spT, attnw, sidx, outimg, n);
    }
    k_fusion_mfma<<<dim3(WW / 16, HH / 8, 2), 256, 0, stream>>>(outimg, wbf, fb, anchor, outp);
}

// Round 5
// 411.385 us; speedup vs baseline: 2.6543x; 1.1198x over previous
//
#include <hip/hip_runtime.h>

typedef unsigned short u16;
typedef unsigned int u32;
typedef __attribute__((ext_vector_type(8))) short bf16x8;
typedef __attribute__((ext_vector_type(4))) float f32x4;

// Problem constants (fixed shapes from setup_inputs)
#define HS   48
#define WSB  48
#define NPIX 2304        // 48*48
#define CCH  128         // c
#define NT   6           // n*t
#define CIN  258         // 2c+2
#define HH   192
#define WW   192

// ws layout in f32 slots (see R3 comment; unchanged)
#define EXTRA_OFF  0ull
#define OUTIMG_OFF 0ull
#define XA_OFF     4718592ull
#define XB_OFF     6488064ull
#define OFFS_OFF   8257536ull
#define ARAW_OFF   8699904ull
#define SPT_OFF    4718592ull
#define ATTNW_OFF  11796480ull
#define SIDX_OFF   12017664ull
#define WBF_OFF    12238848ull

static __device__ __forceinline__ float leaky_f(float v) { return v >= 0.f ? v : 0.1f * v; }
static __device__ __forceinline__ u16 f2bf(float f) {
    u32 u = __float_as_uint(f);
    u = (u + 0x7fffu + ((u >> 16) & 1u)) >> 16;
    return (u16)u;
}
static __device__ __forceinline__ float bf2f(u16 v) {
    u32 u = ((u32)v) << 16;
    return __uint_as_float(u);
}

// ---- K0: pack fusion weights to bf16 [d][oc][ic] ----
__global__ __launch_bounds__(256) void k_wprep(const float* __restrict__ fw, u16* __restrict__ wbf) {
    int i = blockIdx.x * 256 + threadIdx.x;      // 9*128*128 = 147456
    int d = i / 16384;
    int r2 = i & 16383;
    int oc = r2 >> 7, ic = r2 & 127;
    wbf[i] = f2bf(fw[((size_t)oc * 128 + ic) * 9 + d]);
}

// ---- K1: extra[:,0:128] = per-16-channel mean of sp at own pixel ----
__global__ __launch_bounds__(256) void k_avgpool(const float* __restrict__ sp,
                                                 float* __restrict__ extra) {
    int idx = blockIdx.x * 256 + threadIdx.x;
    if (idx >= NT * CCH * NPIX) return;
    int pix = idx % NPIX;
    int cc  = (idx / NPIX) % CCH;
    int nt  = idx / (NPIX * CCH);
    const float* p = sp + ((size_t)nt * 2048 + (size_t)cc * 16) * NPIX + pix;
    float s = 0.f;
#pragma unroll
    for (int k = 0; k < 16; k++) s += p[(size_t)k * NPIX];
    extra[((size_t)nt * CIN + cc) * NPIX + pix] = s * 0.0625f;
}

// ---- K2: extra[:,128:256] = gather of pooled field at flow-sampled pixel; [256:258]=flow ----
__global__ __launch_bounds__(256) void k_extra_rest(const float* __restrict__ flow,
                                                    float* __restrict__ extra) {
    int idx = blockIdx.x * 256 + threadIdx.x;
    if (idx >= NT * 130 * NPIX) return;
    int pix = idx % NPIX;
    int cc  = (idx / NPIX) % 130;
    int nt  = idx / (NPIX * 130);
    float fx = flow[((size_t)nt * 2 + 0) * NPIX + pix];
    float fy = flow[((size_t)nt * 2 + 1) * NPIX + pix];
    if (cc >= 128) {
        extra[((size_t)nt * CIN + 256 + (cc - 128)) * NPIX + pix] = (cc == 128) ? fx : fy;
        return;
    }
    int x = pix % WSB, y = pix / WSB;
    float locx = fx + (float)x;
    float locy = fy + (float)y;
    float gfx = 2.0f * locx / 47.0f - 1.0f;
    float gfy = 2.0f * locy / 47.0f - 1.0f;
    float rx = rintf(((gfx + 1.0f) * 0.5f) * 47.0f);
    float ry = rintf(((gfy + 1.0f) * 0.5f) * 47.0f);
    bool valid = (rx >= 0.f) && (rx <= 47.f) && (ry >= 0.f) && (ry <= 47.f);
    int sx = (int)fminf(fmaxf(rx, 0.f), 47.f);
    int sy = (int)fminf(fmaxf(ry, 0.f), 47.f);
    float v = valid ? extra[((size_t)nt * CIN + cc) * NPIX + sy * WSB + sx] : 0.f;
    extra[((size_t)nt * CIN + 128 + cc) * NPIX + pix] = v;
}

// ---- K3: 1x1 conv 258->64 + leaky, both nets (z = net*4+ocg) ----
__global__ __launch_bounds__(256) void k_conv1x1_l0(const float* __restrict__ extra,
                                                    const float* __restrict__ w_so, const float* __restrict__ b_so,
                                                    const float* __restrict__ w_aw, const float* __restrict__ b_aw,
                                                    float* __restrict__ xa) {
    __shared__ float ws_[16 * CIN];
    int tile = blockIdx.x;
    int nt   = blockIdx.y;
    int z    = blockIdx.z;
    int net = z >> 2, ocg = z & 3;
    const float* wsel = net ? w_aw : w_so;
    const float* bsel = net ? b_aw : b_so;
    for (int i = threadIdx.x; i < 16 * CIN; i += 256)
        ws_[i] = wsel[(size_t)(ocg * 16) * CIN + i];
    __syncthreads();
    int pix = tile * 256 + threadIdx.x;
    float acc[16];
#pragma unroll
    for (int o = 0; o < 16; o++) acc[o] = bsel[ocg * 16 + o];
    const float* in = extra + (size_t)nt * CIN * NPIX + pix;
    for (int ci = 0; ci < CIN; ci++) {
        float v = in[(size_t)ci * NPIX];
#pragma unroll
        for (int o = 0; o < 16; o++) acc[o] = fmaf(ws_[o * CIN + ci], v, acc[o]);
    }
    float* op = xa + (((size_t)net * NT + nt) * 64 + ocg * 16) * NPIX + pix;
#pragma unroll
    for (int o = 0; o < 16; o++) op[(size_t)o * NPIX] = leaky_f(acc[o]);
}

// ---- K4: 3x3 conv 64->64 pad1 + leaky, both nets (R5: scalar weights) ----
// grid (9, 6, 16): z = net*8 + ocg (8 oc per group). 864 blocks.
// Weights read from GLOBAL with block-uniform indices -> compiler emits
// s_load into SGPRs (scalar pipe). LDS holds only the input tile chunk
// [16ic][18][19] (21.9 KB). Per ic: 9 ds_read + 72 v_fma -> VALU-bound.
__global__ __launch_bounds__(256) void k_conv3x3(const float* __restrict__ xin,
                                                 const float* __restrict__ w_so, const float* __restrict__ b_so,
                                                 const float* __restrict__ w_aw, const float* __restrict__ b_aw,
                                                 float* __restrict__ xout) {
    __shared__ float tile[16][18][19];
    int tid = threadIdx.x;
    int tx = tid & 15, ty = tid >> 4;
    int tileid = blockIdx.x;
    int tx0 = (tileid % 3) * 16, ty0 = (tileid / 3) * 16;
    int nt = blockIdx.y;
    int z = blockIdx.z;
    int net = z >> 3, ocg = z & 7;
    const float* w = net ? w_aw : w_so;
    const float* b = net ? b_aw : b_so;
    const float* in = xin + ((size_t)net * NT + nt) * 64 * NPIX;
    const float* wbase = w + (size_t)(ocg * 8) * 576;   // [8oc][64ic][9] slab

    float acc[8];
#pragma unroll
    for (int o = 0; o < 8; o++) acc[o] = b[ocg * 8 + o];

    for (int c0 = 0; c0 < 64; c0 += 16) {
        __syncthreads();   // prior compute done
        for (int i = tid; i < 16 * 324; i += 256) {
            int ic = i / 324;
            int r = i - ic * 324;
            int iy = r / 18, ix = r - iy * 18;
            int gy = ty0 + iy - 1, gx = tx0 + ix - 1;
            float v = 0.f;
            if (gy >= 0 && gy < HS && gx >= 0 && gx < WSB)
                v = in[(size_t)(c0 + ic) * NPIX + gy * WSB + gx];
            tile[ic][iy][ix] = v;
        }
        __syncthreads();
#pragma unroll 4
        for (int ic = 0; ic < 16; ic++) {
            float pv[3][3];
#pragma unroll
            for (int dy = 0; dy < 3; dy++)
#pragma unroll
                for (int dx = 0; dx < 3; dx++)
                    pv[dy][dx] = tile[ic][ty + dy][tx + dx];
            const float* wp = wbase + (size_t)(c0 + ic) * 9;   // uniform -> s_load
#pragma unroll
            for (int o = 0; o < 8; o++)
#pragma unroll
                for (int tap = 0; tap < 9; tap++)
                    acc[o] = fmaf(wp[(size_t)o * 576 + tap], pv[tap / 3][tap % 3], acc[o]);
        }
    }

    int pix = (ty0 + ty) * WSB + (tx0 + tx);
    float* op = xout + (((size_t)net * NT + nt) * 64 + ocg * 8) * NPIX + pix;
#pragma unroll
    for (int o = 0; o < 8; o++) op[(size_t)o * NPIX] = leaky_f(acc[o]);
}

// ---- K5: final 1x1 convs ----
__global__ __launch_bounds__(256) void k_conv1x1_l3(const float* __restrict__ xin,
                                                    const float* __restrict__ w_so, const float* __restrict__ b_so,
                                                    const float* __restrict__ w_aw, const float* __restrict__ b_aw,
                                                    float* __restrict__ offs, float* __restrict__ araw) {
    int pix = blockIdx.x * 256 + threadIdx.x;
    int nt = blockIdx.y;
    int net = blockIdx.z;
    const float* in = xin + ((size_t)net * NT + nt) * 64 * NPIX + pix;
    if (net == 0) {
        float acc[32];
#pragma unroll
        for (int o = 0; o < 32; o++) acc[o] = b_so[o];
        for (int ci = 0; ci < 64; ci++) {
            float v = in[(size_t)ci * NPIX];
#pragma unroll
            for (int o = 0; o < 32; o++) acc[o] = fmaf(w_so[o * 64 + ci], v, acc[o]);
        }
#pragma unroll
        for (int o = 0; o < 32; o++) offs[((size_t)nt * 32 + o) * NPIX + pix] = acc[o];
    } else {
        float acc[16];
#pragma unroll
        for (int o = 0; o < 16; o++) acc[o] = b_aw[o];
        for (int ci = 0; ci < 64; ci++) {
            float v = in[(size_t)ci * NPIX];
#pragma unroll
            for (int o = 0; o < 16; o++) acc[o] = fmaf(w_aw[o * 64 + ci], v, acc[o]);
        }
#pragma unroll
        for (int o = 0; o < 16; o++) araw[((size_t)nt * 16 + o) * NPIX + pix] = acc[o];
    }
}

// ---- K6: softmax over 12 (t,p) + sample-index precompute ----
__global__ __launch_bounds__(256) void k_softmax_idx(const float* __restrict__ araw,
                                                     const float* __restrict__ offs,
                                                     const float* __restrict__ flow,
                                                     float* __restrict__ attnw, int* __restrict__ sidx) {
    int idx = blockIdx.x * 256 + threadIdx.x;
    if (idx >= 2 * 4 * NPIX) return;
    int pix  = idx % NPIX;
    int head = (idx / NPIX) & 3;
    int n    = idx / (NPIX * 4);
    int x = pix % WSB, y = pix / WSB;
    float a[12];
#pragma unroll
    for (int t = 0; t < 3; t++)
#pragma unroll
        for (int p = 0; p < 4; p++)
            a[t * 4 + p] = araw[(((size_t)(n * 3 + t)) * 16 + head * 4 + p) * NPIX + pix];
    float mx = a[0];
#pragma unroll
    for (int k = 1; k < 12; k++) mx = fmaxf(mx, a[k]);
    float ssum = 0.f;
#pragma unroll
    for (int k = 0; k < 12; k++) { a[k] = expf(a[k] - mx); ssum += a[k]; }
    float inv = 1.0f / ssum;
#pragma unroll
    for (int t = 0; t < 3; t++) {
        int nt = n * 3 + t;
        float fx = flow[((size_t)nt * 2 + 0) * NPIX + pix];
        float fy = flow[((size_t)nt * 2 + 1) * NPIX + pix];
        float locx = fx + (float)x;
        float locy = fy + (float)y;
#pragma unroll
        for (int p = 0; p < 4; p++) {
            int hp = head * 4 + p;
            float gx_ = locx + offs[(((size_t)nt) * 32 + hp * 2 + 0) * NPIX + pix];
            float gy_ = locy + offs[(((size_t)nt) * 32 + hp * 2 + 1) * NPIX + pix];
            float ngx = 2.0f * gx_ / 48.0f - 1.0f;
            float ngy = 2.0f * gy_ / 48.0f - 1.0f;
            float rx = rintf(((ngx + 1.0f) * 0.5f) * 47.0f);
            float ry = rintf(((ngy + 1.0f) * 0.5f) * 47.0f);
            bool valid = (rx >= 0.f) && (rx <= 47.f) && (ry >= 0.f) && (ry <= 47.f);
            int sx = (int)fminf(fmaxf(rx, 0.f), 47.f);
            int sy = (int)fminf(fmaxf(ry, 0.f), 47.f);
            int k = t * 4 + p;
            attnw[(size_t)idx * 12 + k] = valid ? a[k] * inv : 0.f;
            sidx[(size_t)idx * 12 + k]  = sy * WSB + sx;
        }
    }
}

// ---- K6.5: per-n transpose sp[nt][2048][2304] f32 -> spT[t][pix][2048] bf16 ----
__global__ __launch_bounds__(256) void k_transpose(const float* __restrict__ sp,
                                                   u16* __restrict__ spT, int n) {
    __shared__ float tile[64][65];
    int tid = threadIdx.x;
    int pix0 = blockIdx.x * 64;    // 36 tiles
    int ch0  = blockIdx.y * 64;    // 32 tiles
    int tl   = blockIdx.z;         // 0..2 (t within n)
    int nt = n * 3 + tl;
    const float* base = sp + ((size_t)nt * 2048 + ch0) * NPIX + pix0;
#pragma unroll
    for (int k = 0; k < 16; k++) {
        int row = k * 4 + (tid >> 6);
        int col = tid & 63;
        tile[row][col] = base[(size_t)row * NPIX + col];
    }
    __syncthreads();
#pragma unroll
    for (int k = 0; k < 2; k++) {
        int task = k * 256 + tid;
        int pl = task >> 3;           // pix_local 0..63
        int c0 = (task & 7) * 8;      // ch chunk
        u16 pk[8];
#pragma unroll
        for (int j = 0; j < 8; j++) pk[j] = f2bf(tile[c0 + j][pl]);
        *reinterpret_cast<int4*>(spT + ((size_t)tl * NPIX + pix0 + pl) * 2048 + ch0 + c0) =
            *reinterpret_cast<const int4*>(pk);
    }
}

// ---- K7: coalesced 12-term gather from spT -> bf16 NHWC outimg (one wave per head) ----
__global__ __launch_bounds__(256) void k_gather2(const u16* __restrict__ spT,
                                                 const float* __restrict__ attnw,
                                                 const int* __restrict__ sidx,
                                                 u16* __restrict__ outimg, int n) {
    __shared__ u16 sArr[2048 + 128];
    int tid = threadIdx.x;
    int pix = blockIdx.x;
    int y = pix / WSB, x = pix % WSB;
    int h = tid >> 6;      // head = wave id
    int lane = tid & 63;
    size_t ab = ((size_t)(n * 4 + h) * NPIX + pix) * 12;
    float acc[8] = {};
#pragma unroll
    for (int t = 0; t < 3; t++) {
#pragma unroll
        for (int p = 0; p < 4; p++) {
            int k = t * 4 + p;
            float w = attnw[ab + k];
            int idx = sidx[ab + k];
            bf16x8 v = *reinterpret_cast<const bf16x8*>(
                spT + ((size_t)t * NPIX + idx) * 2048 + h * 512 + lane * 8);
#pragma unroll
            for (int j = 0; j < 8; j++)
                acc[j] = fmaf(w, bf2f((u16)v[j]), acc[j]);
        }
    }
    int c0 = h * 512 + lane * 8;
    int si = c0 + (c0 >> 4);
    u16 pk[8];
#pragma unroll
    for (int j = 0; j < 8; j++) pk[j] = f2bf(acc[j]);
    *reinterpret_cast<int4*>(&sArr[si]) = *reinterpret_cast<const int4*>(pk);
    __syncthreads();
    int opix = tid >> 4;
    int oc0 = (tid & 15) * 8;
    u16 ov[8];
#pragma unroll
    for (int j = 0; j < 8; j++) {
        int oc = oc0 + j;
        int ch = (oc >> 5) * 512 + (oc & 31) * 16 + opix;
        ov[j] = sArr[ch + (ch >> 4)];
    }
    int hq = y * 4 + (opix >> 2);
    int wq = x * 4 + (opix & 3);
    *reinterpret_cast<int4*>(outimg + (((size_t)(n * HH + hq) * WW + wq) << 7) + oc0) =
        *reinterpret_cast<const int4*>(ov);
}

// ---- K8: fusion 3x3 conv 128->128 via bf16 MFMA implicit GEMM ----
__global__ __launch_bounds__(256, 2) void k_fusion_mfma(const u16* __restrict__ img,   // bf16 NHWC
                                                        const u16* __restrict__ wbf,   // bf16 [9][oc][ic]
                                                        const float* __restrict__ bias,
                                                        const float* __restrict__ anchor,
                                                        float* __restrict__ out) {
    __shared__ __align__(16) u16 lds_in[180 * 128];
    __shared__ __align__(16) u16 lds_w[128 * 128];

    const int tid = threadIdx.x;
    const int px0 = blockIdx.x * 16;
    const int py0 = blockIdx.y * 8;
    const int nb  = blockIdx.z;
    const int lane = tid & 63;
    const int wave = tid >> 6;
    const int wm = wave >> 1, wn = wave & 1;
    const int r = lane & 15, g = lane >> 4;

    char* lin_b = reinterpret_cast<char*>(lds_in);
    char* lw_b  = reinterpret_cast<char*>(lds_w);

    for (int i = tid; i < 180 * 16; i += 256) {
        int p = i >> 4, c16 = i & 15;
        int hy = p / 18, hx = p % 18;
        int gy = py0 + hy - 1, gx = px0 + hx - 1;
        int4 v = make_int4(0, 0, 0, 0);
        if (gy >= 0 && gy < HH && gx >= 0 && gx < WW)
            v = *reinterpret_cast<const int4*>(img + (((size_t)(nb * HH + gy) * WW + gx) << 7) + (c16 << 3));
        *reinterpret_cast<int4*>(lin_b + p * 256 + (((c16 ^ (p & 7)) << 4))) = v;
    }

    int pym[4], pxm[4], ocn[4];
#pragma unroll
    for (int m = 0; m < 4; m++) { int p = wm * 64 + m * 16 + r; pym[m] = p >> 4; pxm[m] = p & 15; }
#pragma unroll
    for (int n = 0; n < 4; n++) ocn[n] = wn * 64 + n * 16 + r;

    f32x4 acc[4][4] = {};
    int4 wr[8];
#pragma unroll
    for (int q = 0; q < 8; q++)
        wr[q] = *reinterpret_cast<const int4*>(wbf + (size_t)(tid + q * 256) * 8);

    for (int d = 0; d < 9; d++) {
#pragma unroll
        for (int q = 0; q < 8; q++) {
            int j = tid + q * 256;
            int oc = j >> 4, c16 = j & 15;
            *reinterpret_cast<int4*>(lw_b + oc * 256 + (((c16 ^ (oc & 7)) << 4))) = wr[q];
        }
        __syncthreads();
        if (d < 8) {
#pragma unroll
            for (int q = 0; q < 8; q++)
                wr[q] = *reinterpret_cast<const int4*>(wbf + (size_t)(d + 1) * 16384 + (size_t)(tid + q * 256) * 8);
        }
        int dy = d / 3, dx = d % 3;
#pragma unroll
        for (int kc = 0; kc < 4; kc++) {
            int c16 = kc * 4 + g;
            bf16x8 a[4], b[4];
#pragma unroll
            for (int m = 0; m < 4; m++) {
                int hp = (pym[m] + dy) * 18 + (pxm[m] + dx);
                a[m] = *reinterpret_cast<const bf16x8*>(lin_b + hp * 256 + (((c16 ^ (hp & 7)) << 4)));
            }
#pragma unroll
            for (int n = 0; n < 4; n++)
                b[n] = *reinterpret_cast<const bf16x8*>(lw_b + ocn[n] * 256 + (((c16 ^ (ocn[n] & 7)) << 4)));
#pragma unroll
            for (int m = 0; m < 4; m++)
#pragma unroll
                for (int n = 0; n < 4; n++)
                    acc[m][n] = __builtin_amdgcn_mfma_f32_16x16x32_bf16(a[m], b[n], acc[m][n], 0, 0, 0);
        }
        __syncthreads();
    }

    float* buf = reinterpret_cast<float*>(lds_w);
    for (int mg = 0; mg < 8; mg++) {
        if (wm == (mg >> 2)) {
            int m = mg & 3;
#pragma unroll
            for (int n = 0; n < 4; n++) {
                int oc = ocn[n];
#pragma unroll
                for (int reg = 0; reg < 4; reg++)
                    buf[oc * 17 + g * 4 + reg] = acc[m][n][reg];
            }
        }
        __syncthreads();
        {
            int pxl = tid & 15;
            int ocq = tid >> 4;
            int gy = py0 + mg;
#pragma unroll
            for (int q = 0; q < 8; q++) {
                int oc = ocq + q * 16;
                float v = buf[oc * 17 + pxl];
                size_t oa = ((size_t)(nb * CCH + oc)) * (HH * WW) + (size_t)gy * WW + px0 + pxl;
                out[oa] = v + bias[oc] + anchor[oa];
            }
        }
        __syncthreads();
    }
}

extern "C" void kernel_launch(void* const* d_in, const int* in_sizes, int n_in,
                              void* d_out, int out_size, void* d_ws, size_t ws_size,
                              hipStream_t stream) {
    (void)in_sizes; (void)n_in; (void)out_size; (void)ws_size;
    const float* anchor = (const float*)d_in[1];
    const float* sp     = (const float*)d_in[2];
    const float* flow   = (const float*)d_in[3];
    const float* so_w0 = (const float*)d_in[4];  const float* so_b0 = (const float*)d_in[5];
    const float* so_w1 = (const float*)d_in[6];  const float* so_b1 = (const float*)d_in[7];
    const float* so_w2 = (const float*)d_in[8];  const float* so_b2 = (const float*)d_in[9];
    const float* so_w3 = (const float*)d_in[10]; const float* so_b3 = (const float*)d_in[11];
    const float* aw_w0 = (const float*)d_in[12]; const float* aw_b0 = (const float*)d_in[13];
    const float* aw_w1 = (const float*)d_in[14]; const float* aw_b1 = (const float*)d_in[15];
    const float* aw_w2 = (const float*)d_in[16]; const float* aw_b2 = (const float*)d_in[17];
    const float* aw_w3 = (const float*)d_in[18]; const float* aw_b3 = (const float*)d_in[19];
    const float* fw    = (const float*)d_in[20]; const float* fb    = (const float*)d_in[21];

    float* ws     = (float*)d_ws;
    float* extra  = ws + EXTRA_OFF;
    float* xa     = ws + XA_OFF;
    float* xb     = ws + XB_OFF;
    float* offs   = ws + OFFS_OFF;
    float* araw   = ws + ARAW_OFF;
    float* attnw  = ws + ATTNW_OFF;
    int*   sidx   = (int*)(ws + SIDX_OFF);
    u16*   wbf    = (u16*)(ws + WBF_OFF);
    u16*   spT    = (u16*)(ws + SPT_OFF);
    u16*   outimg = (u16*)(ws + OUTIMG_OFF);
    float* outp   = (float*)d_out;

    k_wprep<<<dim3(576), 256, 0, stream>>>(fw, wbf);
    k_avgpool<<<dim3((NT * CCH * NPIX + 255) / 256), 256, 0, stream>>>(sp, extra);
    k_extra_rest<<<dim3((NT * 130 * NPIX + 255) / 256), 256, 0, stream>>>(flow, extra);
    k_conv1x1_l0<<<dim3(9, 6, 8), 256, 0, stream>>>(extra, so_w0, so_b0, aw_w0, aw_b0, xa);
    k_conv3x3<<<dim3(9, 6, 16), 256, 0, stream>>>(xa, so_w1, so_b1, aw_w1, aw_b1, xb);
    k_conv3x3<<<dim3(9, 6, 16), 256, 0, stream>>>(xb, so_w2, so_b2, aw_w2, aw_b2, xa);
    k_conv1x1_l3<<<dim3(9, 6, 2), 256, 0, stream>>>(xa, so_w3, so_b3, aw_w3, aw_b3, offs, araw);
    k_softmax_idx<<<dim3((2 * 4 * NPIX + 255) / 256), 256, 0, stream>>>(araw, offs, flow, attnw, sidx);
    for (int n = 0; n < 2; n++) {
        k_transpose<<<dim3(36, 32, 3), 256, 0, stream>>>(sp, spT, n);
        k_gather2<<<dim3(NPIX), 256, 0, stream>>>(spT, attnw, sidx, outimg, n);
    }
    k_fusion_mfma<<<dim3(WW / 16, HH / 8, 2), 256, 0, stream>>>(outimg, wbf, fb, anchor, outp);
}